// Round 13
// baseline (374.205 us; speedup 1.0000x reference)
//
#include <hip/hip_runtime.h>
#include <hip/hip_bf16.h>

using bf16 = __hip_bfloat16;

#define DEV_INLINE __device__ __forceinline__

// Problem constants
constexpr int B_  = 4;
constexpr int LQ  = 3000;
constexpr int LK  = 750;
constexpr int NH_ = 4;
constexpr float EPSF = 1e-6f;

// LDS pitch in uint2 elements per d4-row (>=750, odd) — awg kernel.
constexpr int PITCH = 751;

// Workspace layout (fp32 elements).
constexpr size_t WS_KV = 0;        // 6 x B*LK*64 = 1,152,000
constexpr size_t WS_XB = 1152000;  // B*LQ*64 = 768,000 (unused)
constexpr size_t WS_QP = 1920000;  // 768,000 (cal qp f32; later mgan qp packed f16)
constexpr size_t WS_AO = 2688000;  // 768,000
constexpr size_t WS_QN = 3456000;  // 768,000
constexpr size_t WS_SG = 4224000;  // 768,000

typedef _Float16 half2_t __attribute__((ext_vector_type(2)));
typedef _Float16 half4_t __attribute__((ext_vector_type(4)));
typedef float    f32x4   __attribute__((ext_vector_type(4)));

// correct gfx950 spelling (per compiler diagnostic r14): ...16x16x16f16
#define MFMA16(a, b, c) __builtin_amdgcn_mfma_f32_16x16x16f16((a), (b), (c), 0, 0, 0)

DEV_INLINE float sigmoidf(float x) { return 1.f / (1.f + __expf(-x)); }

DEV_INLINE unsigned int packh2(float a, float b) {
  half2_t h = { (_Float16)a, (_Float16)b };
  unsigned int u; __builtin_memcpy(&u, &h, 4); return u;
}
DEV_INLINE half2_t u2h(unsigned int u) {
  half2_t h; __builtin_memcpy(&h, &u, 4); return h;
}
DEV_INLINE unsigned short f2h(float f) {
  _Float16 h = (_Float16)f;
  unsigned short u; __builtin_memcpy(&u, &h, 2); return u;
}
// half4 from two 4-byte-aligned uints at p, p+2 (f16 units)
DEV_INLINE half4_t h4_from(const unsigned short* p) {
  unsigned int lo = *(const unsigned int*)p;
  unsigned int hi = *(const unsigned int*)(p + 2);
  unsigned long long v = ((unsigned long long)hi << 32) | lo;
  half4_t h; __builtin_memcpy(&h, &v, 8); return h;
}
// one v_dot2_f32_f16: acc + k.x*q.x + k.y*q.y
DEV_INLINE float dot2(unsigned int kw, half2_t qh, float acc) {
  return __builtin_amdgcn_fdot2(u2h(kw), qh, acc, false);
}

DEV_INLINE unsigned int f2sort(float f) {
  int ib = __float_as_int(f);
  return (unsigned int)(ib ^ ((ib >> 31) | 0x80000000));
}
// inverse of f2sort
DEV_INLINE float sort2f(unsigned int u) {
  const int ib = (u & 0x80000000u) ? (int)(u ^ 0x80000000u) : (int)~u;
  return __int_as_float(ib);
}

DEV_INLINE unsigned int bcastu(unsigned int v) {
  return (unsigned int)__builtin_amdgcn_readfirstlane((int)v);
}

// 4 independent descending bitonic sorts (one value/lane each) across the
// 64-lane wave — DPP/permute + VALU, ILP-4 by construction.
DEV_INLINE void sort64u_desc4(unsigned int v[4]) {
  const int lane = threadIdx.x & 63;
  #pragma unroll
  for (int k = 2; k <= 64; k <<= 1) {
    #pragma unroll
    for (int j = k >> 1; j > 0; j >>= 1) {
      const bool takeMax = ((lane & j) == 0) == ((lane & k) == 0);
      #pragma unroll
      for (int r = 0; r < 4; ++r) {
        const unsigned int o = __shfl_xor(v[r], j);
        v[r] = (takeMax == (v[r] > o)) ? v[r] : o;
      }
    }
  }
}

DEV_INLINE float row_ln(float v, float g, float b) {
  float s1 = v, s2 = v * v;
  #pragma unroll
  for (int off = 32; off > 0; off >>= 1) {
    s1 += __shfl_xor(s1, off);
    s2 += __shfl_xor(s2, off);
  }
  const float m   = s1 * (1.f / 64.f);
  const float var = s2 * (1.f / 64.f) - m * m;
  return (v - m) * rsqrtf(var + EPSF) * g + b;
}

// ---------------------------------------------------------------------------
// Merged projections: y<6 -> K/V of enc (188 blocks used); y==6 -> q-proj
// (750 blocks). 16 rows/block, 4 rows/thread, coalesced direct-L2 weights.
// R13: y==0 (cal K) NOW ALSO PACKED f16 (joins y==2/4) — cross_attn's K
// staging becomes a pure copy (no packh2) and K fetch bytes halve. Values
// bit-identical (same packh2 of the same acc).
// ---------------------------------------------------------------------------
__global__ __launch_bounds__(256) void kvq_proj_kernel(
    const float* __restrict__ enc, const float* __restrict__ q,
    const float* __restrict__ calWq,
    const float* __restrict__ calWk, const float* __restrict__ calWv,
    const float* __restrict__ mWk, const float* __restrict__ mWv,
    float* __restrict__ kv, float* __restrict__ qp)
{
  const int y = blockIdx.y;
  if (y < 6 && blockIdx.x >= 188) return;
  __shared__ __align__(16) float xs[16][64];
  const int t = threadIdx.x, rr = t >> 6, cc = t & 63;
  const float* W;
  const float* src;
  float* dst;
  float scale = 1.f;
  int nrows = 3000;
  switch (y) {
    case 0: W = calWk; src = enc; dst = kv;               break;
    case 1: W = calWv; src = enc; dst = kv + 192000;      break;
    case 2: W = mWk;        src = enc; dst = kv + 384000; break;
    case 3: W = mWv;        src = enc; dst = kv + 576000; break;
    case 4: W = mWk + 4096; src = enc; dst = kv + 768000; break;
    case 5: W = mWv + 4096; src = enc; dst = kv + 960000; break;
    default: W = calWq; src = q; dst = qp; scale = 0.25f; nrows = 12000; break;
  }
  const bool packK = (y == 0) || (y == 2) || (y == 4);
  const int base = blockIdx.x * 16;
  {
    const int grow = base + (t >> 4);
    float4 v = {0.f, 0.f, 0.f, 0.f};
    if (grow < nrows) v = *(const float4*)&src[(size_t)grow * 64 + (t & 15) * 4];
    ((float4*)xs)[t] = v;
  }
  __syncthreads();
  float acc[4] = {0.f, 0.f, 0.f, 0.f};
  #pragma unroll 16
  for (int c = 0; c < 64; ++c) {
    const float w = W[c * 64 + cc];
    #pragma unroll
    for (int p = 0; p < 4; ++p) acc[p] = fmaf(xs[p * 4 + rr][c], w, acc[p]);
  }
  #pragma unroll
  for (int p = 0; p < 4; ++p) {
    const int grow = base + p * 4 + rr;
    if (packK) {
      const float accN = __shfl_xor(acc[p], 1);   // partner dim (cc^1)
      if (!(cc & 1) && grow < nrows)
        ((unsigned int*)dst)[(size_t)grow * 32 + (cc >> 1)] = packh2(acc[p], accN);
    } else if (grow < nrows) {
      dst[(size_t)grow * 64 + cc] = acc[p] * scale;
    }
  }
}

// ---------------------------------------------------------------------------
// CROSS attention via MFMA (flash-lite, no max subtraction — logits bounded).
// grid (47, NH, B), block 256 (4 waves); wave owns 16 q-rows (block: 64).
// R13: K arrives PRE-PACKED f16 — staging is a pure uint4 copy.
// ---------------------------------------------------------------------------
__global__ __launch_bounds__(256) void cross_attn_kernel(
    const float* __restrict__ qp, const unsigned int* __restrict__ kp,
    const float* __restrict__ vp, float* __restrict__ ao)
{
  extern __shared__ char smem[];
  unsigned short* Kl = (unsigned short*)smem;       // [750][18]
  unsigned short* Vt = Kl + 750 * 18;               // [16][754]
  unsigned short* Pt = Vt + 16 * 754;               // [4 waves][16][18]

  const int t = threadIdx.x;
  const int h = blockIdx.y, b = blockIdx.z;
  const unsigned int* kslab = kp + ((size_t)(b * LK)) * 32 + h * 8;  // u32 units
  const float* vslab = vp + (size_t)(b * LK) * 64 + h * 16;

  // stage K (pre-packed f16, pitch 18) and V transposed ([d][key])
  for (int k = t; k < LK; k += 256) {
    const uint4* ks = (const uint4*)(kslab + (size_t)k * 32);
    const float4* vs = (const float4*)(vslab + (size_t)k * 64);
    unsigned int* kr = (unsigned int*)(Kl + k * 18);
    const uint4 a0 = ks[0], a1 = ks[1];
    kr[0] = a0.x; kr[1] = a0.y; kr[2] = a0.z; kr[3] = a0.w;
    kr[4] = a1.x; kr[5] = a1.y; kr[6] = a1.z; kr[7] = a1.w;
    #pragma unroll
    for (int q4 = 0; q4 < 4; ++q4) {
      float4 v = vs[q4];
      Vt[(q4 * 4 + 0) * 754 + k] = f2h(v.x);
      Vt[(q4 * 4 + 1) * 754 + k] = f2h(v.y);
      Vt[(q4 * 4 + 2) * 754 + k] = f2h(v.z);
      Vt[(q4 * 4 + 3) * 754 + k] = f2h(v.w);
    }
  }
  // zero V pad keys 750..751 (P is masked there, but 0*NaN would poison O)
  if (t < 32) Vt[(t & 15) * 754 + 750 + (t >> 4)] = 0;
  __syncthreads();

  const int wave = t >> 6, lane = t & 63;
  const int col = lane & 15, quad = lane >> 4;
  const int qbase = blockIdx.x * 64 + wave * 16;
  unsigned short* Pt_w = Pt + wave * 288;   // [16][18]

  // Q A-fragment: A[m=col][k=quad*4+j], constant across tiles
  int qrow = qbase + col; if (qrow >= LQ) qrow = LQ - 1;
  const float* qptr = qp + ((size_t)(b * LQ + qrow)) * 64 + h * 16 + quad * 4;
  half4_t aQ;
  {
    unsigned long long v = ((unsigned long long)packh2(qptr[2], qptr[3]) << 32)
                         | packh2(qptr[0], qptr[1]);
    __builtin_memcpy(&aQ, &v, 8);
  }

  f32x4 O = {0.f, 0.f, 0.f, 0.f};
  float Zp[4] = {0.f, 0.f, 0.f, 0.f};
  const f32x4 zeroC = {0.f, 0.f, 0.f, 0.f};

  for (int tile = 0; tile < 47; ++tile) {
    const int key = tile * 16 + col;
    // B-fragment K^T: B[k=quad*4+j][n=col] = K[key=n][k]
    const half4_t bK = h4_from(Kl + key * 18 + quad * 4);
    f32x4 S = MFMA16(aQ, bK, zeroC);
    // exp + mask (C layout: col=lane&15 -> key, row=quad*4+r)
    const bool valid = key < LK;
    float e0 = valid ? __expf(S[0]) : 0.f;
    float e1 = valid ? __expf(S[1]) : 0.f;
    float e2 = valid ? __expf(S[2]) : 0.f;
    float e3 = valid ? __expf(S[3]) : 0.f;
    Zp[0] += e0; Zp[1] += e1; Zp[2] += e2; Zp[3] += e3;
    // C->A transpose through wave-private LDS tile (barrier-free)
    Pt_w[(quad * 4 + 0) * 18 + col] = f2h(e0);
    Pt_w[(quad * 4 + 1) * 18 + col] = f2h(e1);
    Pt_w[(quad * 4 + 2) * 18 + col] = f2h(e2);
    Pt_w[(quad * 4 + 3) * 18 + col] = f2h(e3);
    const half4_t aP = h4_from(Pt_w + col * 18 + quad * 4);
    // B-fragment V: B[k=quad*4+j][n=col] = V[key=tile*16+quad*4+j][d=col]
    const half4_t bV = h4_from(Vt + col * 754 + tile * 16 + quad * 4);
    O = MFMA16(aP, bV, O);
  }

  // reduce Z across the 16-lane col group (rows quad*4+r live there)
  #pragma unroll
  for (int r = 0; r < 4; ++r) {
    float z = Zp[r];
    z += __shfl_xor(z, 1);
    z += __shfl_xor(z, 2);
    z += __shfl_xor(z, 4);
    z += __shfl_xor(z, 8);
    Zp[r] = z;
  }

  #pragma unroll
  for (int r = 0; r < 4; ++r) {
    const int orow = qbase + quad * 4 + r;
    if (orow < LQ)
      ao[((size_t)(b * LQ + orow)) * 64 + h * 16 + col] = O[r] / Zp[r];
  }
}

// ---------------------------------------------------------------------------
// AWG attention v5.1. grid (94, NH, B), block 512 (8 waves, 4 q-rows/wave).
// R13: q arrives PRE-PACKED f16 (u32 pairs) from ffn_pre/out_pre — 8 loads
// per row instead of 16 loads + 8 packh2. Same bits (producer ran the
// identical packh2). Selection machinery unchanged (proven 58.3 µs core).
// ---------------------------------------------------------------------------
__global__ __launch_bounds__(512) void awg_attn_kernel(
    const unsigned int* __restrict__ qpk, const unsigned int* __restrict__ kp,
    const float* __restrict__ vp, float* __restrict__ ao)
{
  extern __shared__ char smem[];
  uint2*          KT2   = (uint2*)smem;                                      // [4][PITCH] = 24,032 B
  unsigned int*   candV = (unsigned int*)(smem + 4 * PITCH * 8);             // [8][4][64] = 8,192
  unsigned short* candK = (unsigned short*)(smem + 4 * PITCH * 8 + 8192);    // [8][4][64] = 4,096
  float*          selW  = (float*)(smem + 4 * PITCH * 8 + 8192 + 4096);      // [8][4][24] = 3,072
  unsigned short* selK  = (unsigned short*)(smem + 4 * PITCH * 8 + 8192 + 4096 + 3072); // 1,536

  const int t = threadIdx.x;
  const int h = blockIdx.y, b = blockIdx.z;
  const unsigned int* kslab = kp + ((size_t)(b * LK)) * 32 + h * 8;

  for (int k = t; k < LK; k += 512) {
    const uint2* ks = (const uint2*)(kslab + (size_t)k * 32);
    #pragma unroll
    for (int d4 = 0; d4 < 4; ++d4) KT2[d4 * PITCH + k] = ks[d4];
  }
  __syncthreads();

  const int wave = t >> 6, lane = t & 63;
  const unsigned long long below = (1ull << lane) - 1ull;
  unsigned int*   cV = candV + wave * 256;
  unsigned short* cK = candK + wave * 256;
  float*          sW = selW + wave * 96;
  unsigned short* sK = selK + wave * 96;

  // pad select arrays (wave-private; unwritten tail -> exp()==0 in gather)
  sW[lane] = -3.0e38f; sK[lane] = 0;
  if (lane < 32) { sW[64 + lane] = -3.0e38f; sK[64 + lane] = 0; }
  // zero candidate values (pads sort to the tail and never pass >= T)
  #pragma unroll
  for (int r = 0; r < 4; ++r) cV[r * 64 + lane] = 0u;

  const int r0 = blockIdx.x * 32 + wave * 4;
  int r0r = r0; if (r0r > LQ - 4) r0r = LQ - 4;   // clamp reads; stores guarded
  const unsigned int* qrow = qpk + ((size_t)(b * LQ + r0r)) * 32 + h * 8;
  unsigned int qw[4][8];   // wave-uniform packed f16 q -> SGPRs
  #pragma unroll
  for (int r = 0; r < 4; ++r) {
    #pragma unroll
    for (int i = 0; i < 8; ++i)
      qw[r][i] = bcastu(qrow[r * 32 + i]);
  }

  float lg[4][12];
  #pragma unroll
  for (int tt = 0; tt < 12; ++tt) {
    const int k = lane + (tt << 6);
    if (tt < 11 || k < LK) {
      float a0 = 0.f, a1 = 0.f, a2 = 0.f, a3 = 0.f;
      #pragma unroll
      for (int d4 = 0; d4 < 4; ++d4) {
        const uint2 w = KT2[d4 * PITCH + k];
        a0 = dot2(w.x, u2h(qw[0][2 * d4]), a0); a0 = dot2(w.y, u2h(qw[0][2 * d4 + 1]), a0);
        a1 = dot2(w.x, u2h(qw[1][2 * d4]), a1); a1 = dot2(w.y, u2h(qw[1][2 * d4 + 1]), a1);
        a2 = dot2(w.x, u2h(qw[2][2 * d4]), a2); a2 = dot2(w.y, u2h(qw[2][2 * d4 + 1]), a2);
        a3 = dot2(w.x, u2h(qw[3][2 * d4]), a3); a3 = dot2(w.y, u2h(qw[3][2 * d4 + 1]), a3);
      }
      lg[0][tt] = a0; lg[1][tt] = a1; lg[2][tt] = a2; lg[3][tt] = a3;
    } else {
      lg[0][tt] = -3.0e38f; lg[1][tt] = -3.0e38f;
      lg[2][tt] = -3.0e38f; lg[3][tt] = -3.0e38f;
    }
  }

  // per-lane heads (max of this lane's 12 keys) per row
  unsigned int hs[4];
  #pragma unroll
  for (int r = 0; r < 4; ++r) {
    float m = lg[r][0];
    #pragma unroll
    for (int tt = 1; tt < 12; ++tt) m = fmaxf(m, lg[r][tt]);
    hs[r] = f2sort(m);
  }

  // stage 1: sort heads descending -> L = exact 16th largest head
  sort64u_desc4(hs);
  unsigned int L[4];
  #pragma unroll
  for (int r = 0; r < 4; ++r) L[r] = __shfl(hs[r], 15);

  // stage 2: compact candidates (value u32 + key u16)
  int cb[4] = {0, 0, 0, 0};
  #pragma unroll
  for (int tt = 0; tt < 12; ++tt) {
    const int k = lane + (tt << 6);
    #pragma unroll
    for (int r = 0; r < 4; ++r) {
      const unsigned int s = f2sort(lg[r][tt]);
      const bool p = s >= L[r];
      const unsigned long long m = __ballot(p);
      if (p) {
        const int pos = cb[r] + (int)__popcll(m & below);
        if (pos < 64) { cV[r * 64 + pos] = s; cK[r * 64 + pos] = (unsigned short)k; }
      }
      cb[r] += (int)__popcll(m);
    }
  }

  // stage 3: sort candidate VALUES descending -> T@lane15, M@lane0
  unsigned int su[4], so[4];
  #pragma unroll
  for (int r = 0; r < 4; ++r) { su[r] = cV[r * 64 + lane]; so[r] = su[r]; }
  sort64u_desc4(so);
  unsigned int T[4]; float Mv[4];
  #pragma unroll
  for (int r = 0; r < 4; ++r) {
    T[r]  = __shfl(so[r], 15);
    Mv[r] = sort2f(__shfl(so[r], 0));
  }

  // kept set (value >= T; pads su==0 < T always); compact write, cap 24
  #pragma unroll
  for (int r = 0; r < 4; ++r) {
    const bool w = su[r] >= T[r];
    const unsigned long long mw = __ballot(w);
    if (w) {
      const int pos = (int)__popcll(mw & below);
      if (pos < 24) { sW[r * 24 + pos] = sort2f(su[r]); sK[r * 24 + pos] = cK[r * 64 + lane]; }
    }
  }

  // gather: 16 lanes per row (dd = dim), fixed 24 slots, fully unrolled
  const int dd = lane & 15;
  const int rsel = lane >> 4;
  const float ref = (rsel == 0) ? Mv[0] : (rsel == 1) ? Mv[1] : (rsel == 2) ? Mv[2] : Mv[3];
  const float* cwr = sW + rsel * 24;
  const unsigned short* cir = sK + rsel * 24;
  const float* vbase = vp + (size_t)(b * LK) * 64 + h * 16 + dd;
  float acc = 0.f, Z = 0.f;
  #pragma unroll
  for (int j = 0; j < 24; ++j) {
    const float e = __expf(cwr[j] - ref);
    Z += e;
    acc = fmaf(e, vbase[(size_t)cir[j] * 64], acc);
  }
  if (r0 + rsel < LQ)
    ao[((size_t)(b * LQ + r0 + rsel)) * 64 + h * 16 + dd] = acc / Z;
}

// ---------------------------------------------------------------------------
// FUSED cross-FFN + MGAN pre (layer 0). 16 rows/block, grid 750, 4
// rows/thread, coalesced direct-L2 weights. R13: deeper unrolls (grid caps
// occupancy at ~2.9 waves/SIMD, so VGPRs are free to spend on MLP depth);
// qp output PACKED f16 (bit-identical: same packh2 awg would have run).
// ---------------------------------------------------------------------------
__global__ __launch_bounds__(256) void ffn_pre_kernel(
    const float* __restrict__ ao, const float* __restrict__ qres,
    const float* __restrict__ Wo,
    const float* __restrict__ g1, const float* __restrict__ b1n,
    const float* __restrict__ W1, const float* __restrict__ bb1,
    const float* __restrict__ W2, const float* __restrict__ bb2,
    const float* __restrict__ g2, const float* __restrict__ b2n,
    const float* __restrict__ lng, const float* __restrict__ lnb,
    const float* __restrict__ fc1W, const float* __restrict__ fc1b,
    const float* __restrict__ fc2W, const float* __restrict__ fc2b,
    const float* __restrict__ Wq,
    float* __restrict__ qn, float* __restrict__ sg,
    unsigned int* __restrict__ qp)
{
  __shared__ float xs[16][64];
  __shared__ float hsm[16][256];
  const int t = threadIdx.x, rr = t >> 6, cc = t & 63;
  const size_t base = (size_t)blockIdx.x * 16;
  for (int i = t; i < 1024; i += 256) xs[i >> 6][i & 63] = ao[base * 64 + i];
  __syncthreads();
  float acc[4];
  #pragma unroll
  for (int p = 0; p < 4; ++p) acc[p] = 0.f;
  #pragma unroll 16
  for (int c = 0; c < 64; ++c) {
    const float w = Wo[c * 64 + cc];
    #pragma unroll
    for (int p = 0; p < 4; ++p) acc[p] = fmaf(xs[p * 4 + rr][c], w, acc[p]);
  }
  #pragma unroll
  for (int p = 0; p < 4; ++p) acc[p] += qres[(base + p * 4 + rr) * 64 + cc];
  __syncthreads();
  float x1[4];
  #pragma unroll
  for (int p = 0; p < 4; ++p) {
    x1[p] = row_ln(acc[p], g1[cc], b1n[cc]);
    xs[p * 4 + rr][cc] = x1[p];
  }
  __syncthreads();
  {
    float hv[16];
    #pragma unroll
    for (int r = 0; r < 16; ++r) hv[r] = 0.f;
    #pragma unroll 8
    for (int c = 0; c < 64; ++c) {
      const float w = W1[c * 256 + t];
      #pragma unroll
      for (int r = 0; r < 16; ++r) hv[r] = fmaf(xs[r][c], w, hv[r]);
    }
    const float bb = bb1[t];
    #pragma unroll
    for (int r = 0; r < 16; ++r) hsm[r][t] = fmaxf(hv[r] + bb, 0.f);
  }
  __syncthreads();
  float acc2[4];
  #pragma unroll
  for (int p = 0; p < 4; ++p) acc2[p] = bb2[cc];
  #pragma unroll 16
  for (int c = 0; c < 256; ++c) {
    const float w = W2[c * 64 + cc];
    #pragma unroll
    for (int p = 0; p < 4; ++p) acc2[p] = fmaf(hsm[p * 4 + rr][c], w, acc2[p]);
  }
  // x = LN(ffn + x1); qn = LN(x) — xs reuse is safe: last xs read was
  // guarded by the post-W1 barrier above.
  float qv[4];
  #pragma unroll
  for (int p = 0; p < 4; ++p) {
    const float xv = row_ln(acc2[p] + x1[p], g2[cc], b2n[cc]);
    qv[p] = row_ln(xv, lng[cc], lnb[cc]);
    qn[(base + p * 4 + rr) * 64 + cc] = qv[p];
  }
  __syncthreads();
  #pragma unroll
  for (int p = 0; p < 4; ++p) xs[p * 4 + rr][cc] = qv[p];
  __syncthreads();
  float d1[4], d2[4];
  #pragma unroll
  for (int p = 0; p < 4; ++p) { d1[p] = fc1b[cc]; d2[p] = fc2b[cc]; }
  #pragma unroll 8
  for (int c = 0; c < 64; ++c) {
    const float w1 = fc1W[c * 64 + cc];
    const float w2 = fc2W[c * 64 + cc];
    #pragma unroll
    for (int p = 0; p < 4; ++p) {
      const float xq = xs[p * 4 + rr][c];
      d1[p] = fmaf(xq, w1, d1[p]);
      d2[p] = fmaf(xq, w2, d2[p]);
    }
  }
  float sv[4];
  #pragma unroll
  for (int p = 0; p < 4; ++p) {
    sv[p] = sigmoidf(d1[p]) * d2[p];
    sg[(base + p * 4 + rr) * 64 + cc] = sv[p];
  }
  __syncthreads();
  #pragma unroll
  for (int p = 0; p < 4; ++p) xs[p * 4 + rr][cc] = sv[p];
  __syncthreads();
  float aq[4];
  #pragma unroll
  for (int p = 0; p < 4; ++p) aq[p] = 0.f;
  #pragma unroll 16
  for (int c = 0; c < 64; ++c) {
    const float w = Wq[c * 64 + cc];
    #pragma unroll
    for (int p = 0; p < 4; ++p) aq[p] = fmaf(xs[p * 4 + rr][c], w, aq[p]);
  }
  #pragma unroll
  for (int p = 0; p < 4; ++p) {
    const float v0 = aq[p] * 0.25f;
    const float vN = __shfl_xor(v0, 1);   // partner dim (cc^1)
    if (!(cc & 1))
      qp[(base + p * 4 + rr) * 32 + (cc >> 1)] = packh2(v0, vN);
  }
}

// ---------------------------------------------------------------------------
// Fused awg_out(layer i) + mgan_pre(layer i+1): x never touches HBM.
// 16 rows/block, grid 750, 4 rows/thread. R13: deeper unrolls; qp packed.
// ---------------------------------------------------------------------------
__global__ __launch_bounds__(256) void out_pre_kernel(
    const float* __restrict__ ao, const float* __restrict__ sg,
    const float* __restrict__ qn, const float* __restrict__ Wo,
    const float* __restrict__ g_, const float* __restrict__ b_,
    const float* __restrict__ lng, const float* __restrict__ lnb,
    const float* __restrict__ W1, const float* __restrict__ bb1,
    const float* __restrict__ W2, const float* __restrict__ bb2,
    const float* __restrict__ Wq,
    float* __restrict__ qn_out, float* __restrict__ sg_out,
    unsigned int* __restrict__ qp_out)
{
  __shared__ float xs[16][64];
  const int t = threadIdx.x, rr = t >> 6, cc = t & 63;
  const size_t base = (size_t)blockIdx.x * 16;
  for (int i = t; i < 1024; i += 256) xs[i >> 6][i & 63] = ao[base * 64 + i];
  __syncthreads();
  float accp[4], sgv[4];
  #pragma unroll
  for (int p = 0; p < 4; ++p) accp[p] = 0.f;
  #pragma unroll 16
  for (int c = 0; c < 64; ++c) {
    const float w = Wo[c * 64 + cc];
    #pragma unroll
    for (int p = 0; p < 4; ++p) accp[p] = fmaf(xs[p * 4 + rr][c], w, accp[p]);
  }
  #pragma unroll
  for (int p = 0; p < 4; ++p) {
    sgv[p] = sg[(base + p * 4 + rr) * 64 + cc];
    accp[p] += sgv[p];
  }
  __syncthreads();
  float qv[4];
  #pragma unroll
  for (int p = 0; p < 4; ++p) {
    const size_t idx = (base + p * 4 + rr) * 64 + cc;
    const float awg = row_ln(accp[p], g_[cc], b_[cc]);
    const float xv = qn[idx] + sgv[p] * sigmoidf(awg);
    qv[p] = row_ln(xv, lng[cc], lnb[cc]);
    qn_out[idx] = qv[p];
    xs[p * 4 + rr][cc] = qv[p];
  }
  __syncthreads();
  float d1[4], d2[4];
  #pragma unroll
  for (int p = 0; p < 4; ++p) { d1[p] = bb1[cc]; d2[p] = bb2[cc]; }
  #pragma unroll 8
  for (int c = 0; c < 64; ++c) {
    const float w1 = W1[c * 64 + cc];
    const float w2 = W2[c * 64 + cc];
    #pragma unroll
    for (int p = 0; p < 4; ++p) {
      const float xv = xs[p * 4 + rr][c];
      d1[p] = fmaf(xv, w1, d1[p]);
      d2[p] = fmaf(xv, w2, d2[p]);
    }
  }
  __syncthreads();
  float sv[4];
  #pragma unroll
  for (int p = 0; p < 4; ++p) {
    sv[p] = sigmoidf(d1[p]) * d2[p];
    sg_out[(base + p * 4 + rr) * 64 + cc] = sv[p];
    xs[p * 4 + rr][cc] = sv[p];
  }
  __syncthreads();
  float aq[4];
  #pragma unroll
  for (int p = 0; p < 4; ++p) aq[p] = 0.f;
  #pragma unroll 16
  for (int c = 0; c < 64; ++c) {
    const float w = Wq[c * 64 + cc];
    #pragma unroll
    for (int p = 0; p < 4; ++p) aq[p] = fmaf(xs[p * 4 + rr][c], w, aq[p]);
  }
  #pragma unroll
  for (int p = 0; p < 4; ++p) {
    const float v0 = aq[p] * 0.25f;
    const float vN = __shfl_xor(v0, 1);   // partner dim (cc^1)
    if (!(cc & 1))
      qp_out[(base + p * 4 + rr) * 32 + (cc >> 1)] = packh2(v0, vN);
  }
}

// ---------------------------------------------------------------------------
// Fused awg_out(layer 1) + head: out = sigmoid(x2 @ fcW + fcb).
// 16 rows/block, grid 750, 4 rows/thread. R13: deeper unroll.
// ---------------------------------------------------------------------------
__global__ __launch_bounds__(256) void out_final_kernel(
    const float* __restrict__ ao, const float* __restrict__ sg,
    const float* __restrict__ qn, const float* __restrict__ Wo,
    const float* __restrict__ g_, const float* __restrict__ b_,
    const float* __restrict__ fw, const float* __restrict__ fb,
    float* __restrict__ out)
{
  __shared__ float xs[16][64];
  const int t = threadIdx.x, rr = t >> 6, cc = t & 63;
  const size_t base = (size_t)blockIdx.x * 16;
  for (int i = t; i < 1024; i += 256) xs[i >> 6][i & 63] = ao[base * 64 + i];
  __syncthreads();
  float accp[4];
  #pragma unroll
  for (int p = 0; p < 4; ++p) accp[p] = 0.f;
  #pragma unroll 16
  for (int c = 0; c < 64; ++c) {
    const float w = Wo[c * 64 + cc];
    #pragma unroll
    for (int p = 0; p < 4; ++p) accp[p] = fmaf(xs[p * 4 + rr][c], w, accp[p]);
  }
  #pragma unroll
  for (int p = 0; p < 4; ++p) {
    const size_t idx = (base + p * 4 + rr) * 64 + cc;
    const float sgv = sg[idx];
    const float a = accp[p] + sgv;
    const float awg = row_ln(a, g_[cc], b_[cc]);
    const float xv = qn[idx] + sgv * sigmoidf(awg);
    float v = xv * fw[cc];
    #pragma unroll
    for (int off = 32; off > 0; off >>= 1) v += __shfl_xor(v, off);
    if (cc == 0) out[base + p * 4 + rr] = sigmoidf(v + fb[0]);
  }
}

// ---------------------------------------------------------------------------
extern "C" void kernel_launch(void* const* d_in, const int* in_sizes, int n_in,
                              void* d_out, int out_size, void* d_ws, size_t ws_size,
                              hipStream_t stream) {
  (void)in_sizes; (void)n_in; (void)out_size; (void)ws_size;

  const float* q     = (const float*)d_in[0];
  const float* enc   = (const float*)d_in[1];
  const float* calWq = (const float*)d_in[2];
  const float* calWk = (const float*)d_in[3];
  const float* calWv = (const float*)d_in[4];
  const float* calWo = (const float*)d_in[5];
  const float* ln1g  = (const float*)d_in[6];
  const float* ln1b  = (const float*)d_in[7];
  const float* W1    = (const float*)d_in[8];
  const float* b1v   = (const float*)d_in[9];
  const float* W2    = (const float*)d_in[10];
  const float* b2v   = (const float*)d_in[11];
  const float* ln2g  = (const float*)d_in[12];
  const float* ln2b  = (const float*)d_in[13];
  const float* mlng  = (const float*)d_in[14];
  const float* mlnb  = (const float*)d_in[15];
  const float* mfc1W = (const float*)d_in[16];
  const float* mfc1b = (const float*)d_in[17];
  const float* mfc2W = (const float*)d_in[18];
  const float* mfc2b = (const float*)d_in[19];
  const float* mWq   = (const float*)d_in[20];
  const float* mWk   = (const float*)d_in[21];
  const float* mWv   = (const float*)d_in[22];
  const float* mWo   = (const float*)d_in[23];
  const float* malng = (const float*)d_in[24];
  const float* malnb = (const float*)d_in[25];
  const float* fcW   = (const float*)d_in[26];
  const float* fcb   = (const float*)d_in[27];
  float* out = (float*)d_out;

  float* ws  = (float*)d_ws;
  float* kv  = ws + WS_KV;
  float* qp  = ws + WS_QP;
  float* aob = ws + WS_AO;
  float* qnb = ws + WS_QN;
  float* sgb = ws + WS_SG;

  const size_t crossLds = (750 * 18 + 16 * 754 + 4 * 288) * 2;        // 53,432 B
  const size_t awgLds   = 4 * PITCH * 8 + 8192 + 4096 + 3072 + 1536;  // 40,928 B

  // 1) all K/V projections + cross q-projection in one dispatch
  //    (K slabs y==0/2/4 stored packed f16; V slabs f32)
  kvq_proj_kernel<<<dim3(750, 7), 256, 0, stream>>>(enc, q, calWq, calWk, calWv,
                                                    mWk, mWv, kv, qp);

  // 2) cross attention (MFMA flash-lite, pre-packed K) + fused FFN+MGAN-pre
  cross_attn_kernel<<<dim3(47, NH_, B_), 256, crossLds, stream>>>(
      qp, (const unsigned int*)kv, kv + 192000, aob);
  ffn_pre_kernel<<<750, 256, 0, stream>>>(aob, q, calWo, ln1g, ln1b,
                                          W1, b1v, W2, b2v, ln2g, ln2b,
                                          mlng, mlnb, mfc1W, mfc1b,
                                          mfc2W, mfc2b, mWq, qnb, sgb,
                                          (unsigned int*)qp);

  // 3) MGAN layer 0 attention + fused out/pre
  awg_attn_kernel<<<dim3(94, NH_, B_), 512, awgLds, stream>>>(
      (const unsigned int*)qp, (const unsigned int*)(kv + 2 * 192000),
      kv + 3 * 192000, aob);
  out_pre_kernel<<<750, 256, 0, stream>>>(aob, sgb, qnb, mWo, malng, malnb,
                                          mlng + 64, mlnb + 64,
                                          mfc1W + 4096, mfc1b + 64,
                                          mfc2W + 4096, mfc2b + 64,
                                          mWq + 4096, qnb, sgb,
                                          (unsigned int*)qp);

  // 4) MGAN layer 1 + head
  awg_attn_kernel<<<dim3(94, NH_, B_), 512, awgLds, stream>>>(
      (const unsigned int*)qp, (const unsigned int*)(kv + 4 * 192000),
      kv + 5 * 192000, aob);
  out_final_kernel<<<750, 256, 0, stream>>>(aob, sgb, qnb, mWo + 4096,
                                            malng + 64, malnb + 64, fcW, fcb, out);
}

// Round 14
// 316.123 us; speedup vs baseline: 1.1837x; 1.1837x over previous
//
#include <hip/hip_runtime.h>
#include <hip/hip_bf16.h>

using bf16 = __hip_bfloat16;

#define DEV_INLINE __device__ __forceinline__

// Problem constants
constexpr int B_  = 4;
constexpr int LQ  = 3000;
constexpr int LK  = 750;
constexpr int NH_ = 4;
constexpr float EPSF = 1e-6f;

// LDS pitch in uint2 elements per d4-row (>=750, odd) — awg kernel.
constexpr int PITCH = 751;

// Workspace layout (fp32 elements).
constexpr size_t WS_KV = 0;        // 6 x B*LK*64 = 1,152,000
constexpr size_t WS_XB = 1152000;  // B*LQ*64 = 768,000 (unused)
constexpr size_t WS_QP = 1920000;  // 768,000 (cal qp f32; later mgan qp packed f16)
constexpr size_t WS_AO = 2688000;  // 768,000
constexpr size_t WS_QN = 3456000;  // 768,000
constexpr size_t WS_SG = 4224000;  // 768,000

typedef _Float16 half2_t __attribute__((ext_vector_type(2)));
typedef _Float16 half4_t __attribute__((ext_vector_type(4)));
typedef float    f32x4   __attribute__((ext_vector_type(4)));

// correct gfx950 spelling (per compiler diagnostic r14): ...16x16x16f16
#define MFMA16(a, b, c) __builtin_amdgcn_mfma_f32_16x16x16f16((a), (b), (c), 0, 0, 0)

DEV_INLINE float sigmoidf(float x) { return 1.f / (1.f + __expf(-x)); }

DEV_INLINE unsigned int packh2(float a, float b) {
  half2_t h = { (_Float16)a, (_Float16)b };
  unsigned int u; __builtin_memcpy(&u, &h, 4); return u;
}
DEV_INLINE half2_t u2h(unsigned int u) {
  half2_t h; __builtin_memcpy(&h, &u, 4); return h;
}
DEV_INLINE unsigned short f2h(float f) {
  _Float16 h = (_Float16)f;
  unsigned short u; __builtin_memcpy(&u, &h, 2); return u;
}
// half4 from two 4-byte-aligned uints at p, p+2 (f16 units)
DEV_INLINE half4_t h4_from(const unsigned short* p) {
  unsigned int lo = *(const unsigned int*)p;
  unsigned int hi = *(const unsigned int*)(p + 2);
  unsigned long long v = ((unsigned long long)hi << 32) | lo;
  half4_t h; __builtin_memcpy(&h, &v, 8); return h;
}
// one v_dot2_f32_f16: acc + k.x*q.x + k.y*q.y
DEV_INLINE float dot2(unsigned int kw, half2_t qh, float acc) {
  return __builtin_amdgcn_fdot2(u2h(kw), qh, acc, false);
}

DEV_INLINE unsigned int f2sort(float f) {
  int ib = __float_as_int(f);
  return (unsigned int)(ib ^ ((ib >> 31) | 0x80000000));
}
// inverse of f2sort
DEV_INLINE float sort2f(unsigned int u) {
  const int ib = (u & 0x80000000u) ? (int)(u ^ 0x80000000u) : (int)~u;
  return __int_as_float(ib);
}

DEV_INLINE unsigned int bcastu(unsigned int v) {
  return (unsigned int)__builtin_amdgcn_readfirstlane((int)v);
}

// 4 independent descending bitonic sorts (one value/lane each) across the
// 64-lane wave — DPP/permute + VALU, ILP-4 by construction.
DEV_INLINE void sort64u_desc4(unsigned int v[4]) {
  const int lane = threadIdx.x & 63;
  #pragma unroll
  for (int k = 2; k <= 64; k <<= 1) {
    #pragma unroll
    for (int j = k >> 1; j > 0; j >>= 1) {
      const bool takeMax = ((lane & j) == 0) == ((lane & k) == 0);
      #pragma unroll
      for (int r = 0; r < 4; ++r) {
        const unsigned int o = __shfl_xor(v[r], j);
        v[r] = (takeMax == (v[r] > o)) ? v[r] : o;
      }
    }
  }
}

DEV_INLINE float row_ln(float v, float g, float b) {
  float s1 = v, s2 = v * v;
  #pragma unroll
  for (int off = 32; off > 0; off >>= 1) {
    s1 += __shfl_xor(s1, off);
    s2 += __shfl_xor(s2, off);
  }
  const float m   = s1 * (1.f / 64.f);
  const float var = s2 * (1.f / 64.f) - m * m;
  return (v - m) * rsqrtf(var + EPSF) * g + b;
}

// ---------------------------------------------------------------------------
// Merged projections: y<6 -> K/V of enc (188 blocks used); y==6 -> q-proj
// (750 blocks). 16 rows/block, 4 rows/thread, coalesced direct-L2 weights,
// R12 unroll depth (R13 proved unroll 16 doubles latency-bound time: the
// scheduler batches loads then drains, instead of pipelining).
// K slabs y==0/2/4 stored PACKED f16 (uint2 per 4 dims) — bit-identical.
// ---------------------------------------------------------------------------
__global__ __launch_bounds__(256) void kvq_proj_kernel(
    const float* __restrict__ enc, const float* __restrict__ q,
    const float* __restrict__ calWq,
    const float* __restrict__ calWk, const float* __restrict__ calWv,
    const float* __restrict__ mWk, const float* __restrict__ mWv,
    float* __restrict__ kv, float* __restrict__ qp)
{
  const int y = blockIdx.y;
  if (y < 6 && blockIdx.x >= 188) return;
  __shared__ __align__(16) float xs[16][64];
  const int t = threadIdx.x, rr = t >> 6, cc = t & 63;
  const float* W;
  const float* src;
  float* dst;
  float scale = 1.f;
  int nrows = 3000;
  switch (y) {
    case 0: W = calWk; src = enc; dst = kv;               break;
    case 1: W = calWv; src = enc; dst = kv + 192000;      break;
    case 2: W = mWk;        src = enc; dst = kv + 384000; break;
    case 3: W = mWv;        src = enc; dst = kv + 576000; break;
    case 4: W = mWk + 4096; src = enc; dst = kv + 768000; break;
    case 5: W = mWv + 4096; src = enc; dst = kv + 960000; break;
    default: W = calWq; src = q; dst = qp; scale = 0.25f; nrows = 12000; break;
  }
  const bool packK = (y == 0) || (y == 2) || (y == 4);
  const int base = blockIdx.x * 16;
  {
    const int grow = base + (t >> 4);
    float4 v = {0.f, 0.f, 0.f, 0.f};
    if (grow < nrows) v = *(const float4*)&src[(size_t)grow * 64 + (t & 15) * 4];
    ((float4*)xs)[t] = v;
  }
  __syncthreads();
  float acc[4] = {0.f, 0.f, 0.f, 0.f};
  #pragma unroll 8
  for (int c = 0; c < 64; ++c) {
    const float w = W[c * 64 + cc];
    #pragma unroll
    for (int p = 0; p < 4; ++p) acc[p] = fmaf(xs[p * 4 + rr][c], w, acc[p]);
  }
  #pragma unroll
  for (int p = 0; p < 4; ++p) {
    const int grow = base + p * 4 + rr;
    if (packK) {
      const float accN = __shfl_xor(acc[p], 1);   // partner dim (cc^1)
      if (!(cc & 1) && grow < nrows)
        ((unsigned int*)dst)[(size_t)grow * 32 + (cc >> 1)] = packh2(acc[p], accN);
    } else if (grow < nrows) {
      dst[(size_t)grow * 64 + cc] = acc[p] * scale;
    }
  }
}

// ---------------------------------------------------------------------------
// CROSS attention via MFMA (flash-lite, no max subtraction — logits bounded).
// grid (47, NH, B), block 256 (4 waves); wave owns 16 q-rows (block: 64).
// K arrives PRE-PACKED f16 — staging is a pure uint4 copy.
// ---------------------------------------------------------------------------
__global__ __launch_bounds__(256) void cross_attn_kernel(
    const float* __restrict__ qp, const unsigned int* __restrict__ kp,
    const float* __restrict__ vp, float* __restrict__ ao)
{
  extern __shared__ char smem[];
  unsigned short* Kl = (unsigned short*)smem;       // [750][18]
  unsigned short* Vt = Kl + 750 * 18;               // [16][754]
  unsigned short* Pt = Vt + 16 * 754;               // [4 waves][16][18]

  const int t = threadIdx.x;
  const int h = blockIdx.y, b = blockIdx.z;
  const unsigned int* kslab = kp + ((size_t)(b * LK)) * 32 + h * 8;  // u32 units
  const float* vslab = vp + (size_t)(b * LK) * 64 + h * 16;

  // stage K (pre-packed f16, pitch 18) and V transposed ([d][key])
  for (int k = t; k < LK; k += 256) {
    const uint4* ks = (const uint4*)(kslab + (size_t)k * 32);
    const float4* vs = (const float4*)(vslab + (size_t)k * 64);
    unsigned int* kr = (unsigned int*)(Kl + k * 18);
    const uint4 a0 = ks[0], a1 = ks[1];
    kr[0] = a0.x; kr[1] = a0.y; kr[2] = a0.z; kr[3] = a0.w;
    kr[4] = a1.x; kr[5] = a1.y; kr[6] = a1.z; kr[7] = a1.w;
    #pragma unroll
    for (int q4 = 0; q4 < 4; ++q4) {
      float4 v = vs[q4];
      Vt[(q4 * 4 + 0) * 754 + k] = f2h(v.x);
      Vt[(q4 * 4 + 1) * 754 + k] = f2h(v.y);
      Vt[(q4 * 4 + 2) * 754 + k] = f2h(v.z);
      Vt[(q4 * 4 + 3) * 754 + k] = f2h(v.w);
    }
  }
  // zero V pad keys 750..751 (P is masked there, but 0*NaN would poison O)
  if (t < 32) Vt[(t & 15) * 754 + 750 + (t >> 4)] = 0;
  __syncthreads();

  const int wave = t >> 6, lane = t & 63;
  const int col = lane & 15, quad = lane >> 4;
  const int qbase = blockIdx.x * 64 + wave * 16;
  unsigned short* Pt_w = Pt + wave * 288;   // [16][18]

  // Q A-fragment: A[m=col][k=quad*4+j], constant across tiles
  int qrow = qbase + col; if (qrow >= LQ) qrow = LQ - 1;
  const float* qptr = qp + ((size_t)(b * LQ + qrow)) * 64 + h * 16 + quad * 4;
  half4_t aQ;
  {
    unsigned long long v = ((unsigned long long)packh2(qptr[2], qptr[3]) << 32)
                         | packh2(qptr[0], qptr[1]);
    __builtin_memcpy(&aQ, &v, 8);
  }

  f32x4 O = {0.f, 0.f, 0.f, 0.f};
  float Zp[4] = {0.f, 0.f, 0.f, 0.f};
  const f32x4 zeroC = {0.f, 0.f, 0.f, 0.f};

  for (int tile = 0; tile < 47; ++tile) {
    const int key = tile * 16 + col;
    // B-fragment K^T: B[k=quad*4+j][n=col] = K[key=n][k]
    const half4_t bK = h4_from(Kl + key * 18 + quad * 4);
    f32x4 S = MFMA16(aQ, bK, zeroC);
    // exp + mask (C layout: col=lane&15 -> key, row=quad*4+r)
    const bool valid = key < LK;
    float e0 = valid ? __expf(S[0]) : 0.f;
    float e1 = valid ? __expf(S[1]) : 0.f;
    float e2 = valid ? __expf(S[2]) : 0.f;
    float e3 = valid ? __expf(S[3]) : 0.f;
    Zp[0] += e0; Zp[1] += e1; Zp[2] += e2; Zp[3] += e3;
    // C->A transpose through wave-private LDS tile (barrier-free)
    Pt_w[(quad * 4 + 0) * 18 + col] = f2h(e0);
    Pt_w[(quad * 4 + 1) * 18 + col] = f2h(e1);
    Pt_w[(quad * 4 + 2) * 18 + col] = f2h(e2);
    Pt_w[(quad * 4 + 3) * 18 + col] = f2h(e3);
    const half4_t aP = h4_from(Pt_w + col * 18 + quad * 4);
    // B-fragment V: B[k=quad*4+j][n=col] = V[key=tile*16+quad*4+j][d=col]
    const half4_t bV = h4_from(Vt + col * 754 + tile * 16 + quad * 4);
    O = MFMA16(aP, bV, O);
  }

  // reduce Z across the 16-lane col group (rows quad*4+r live there)
  #pragma unroll
  for (int r = 0; r < 4; ++r) {
    float z = Zp[r];
    z += __shfl_xor(z, 1);
    z += __shfl_xor(z, 2);
    z += __shfl_xor(z, 4);
    z += __shfl_xor(z, 8);
    Zp[r] = z;
  }

  #pragma unroll
  for (int r = 0; r < 4; ++r) {
    const int orow = qbase + quad * 4 + r;
    if (orow < LQ)
      ao[((size_t)(b * LQ + orow)) * 64 + h * 16 + col] = O[r] / Zp[r];
  }
}

// ---------------------------------------------------------------------------
// AWG attention v5.1. grid (94, NH, B), block 512 (8 waves, 4 q-rows/wave).
// q arrives PRE-PACKED f16 (u32 pairs) — 8 loads/row instead of 16+8 packh2,
// same bits. Selection machinery unchanged (proven 58.3 µs core).
// ---------------------------------------------------------------------------
__global__ __launch_bounds__(512) void awg_attn_kernel(
    const unsigned int* __restrict__ qpk, const unsigned int* __restrict__ kp,
    const float* __restrict__ vp, float* __restrict__ ao)
{
  extern __shared__ char smem[];
  uint2*          KT2   = (uint2*)smem;                                      // [4][PITCH] = 24,032 B
  unsigned int*   candV = (unsigned int*)(smem + 4 * PITCH * 8);             // [8][4][64] = 8,192
  unsigned short* candK = (unsigned short*)(smem + 4 * PITCH * 8 + 8192);    // [8][4][64] = 4,096
  float*          selW  = (float*)(smem + 4 * PITCH * 8 + 8192 + 4096);      // [8][4][24] = 3,072
  unsigned short* selK  = (unsigned short*)(smem + 4 * PITCH * 8 + 8192 + 4096 + 3072); // 1,536

  const int t = threadIdx.x;
  const int h = blockIdx.y, b = blockIdx.z;
  const unsigned int* kslab = kp + ((size_t)(b * LK)) * 32 + h * 8;

  for (int k = t; k < LK; k += 512) {
    const uint2* ks = (const uint2*)(kslab + (size_t)k * 32);
    #pragma unroll
    for (int d4 = 0; d4 < 4; ++d4) KT2[d4 * PITCH + k] = ks[d4];
  }
  __syncthreads();

  const int wave = t >> 6, lane = t & 63;
  const unsigned long long below = (1ull << lane) - 1ull;
  unsigned int*   cV = candV + wave * 256;
  unsigned short* cK = candK + wave * 256;
  float*          sW = selW + wave * 96;
  unsigned short* sK = selK + wave * 96;

  // pad select arrays (wave-private; unwritten tail -> exp()==0 in gather)
  sW[lane] = -3.0e38f; sK[lane] = 0;
  if (lane < 32) { sW[64 + lane] = -3.0e38f; sK[64 + lane] = 0; }
  // zero candidate values (pads sort to the tail and never pass >= T)
  #pragma unroll
  for (int r = 0; r < 4; ++r) cV[r * 64 + lane] = 0u;

  const int r0 = blockIdx.x * 32 + wave * 4;
  int r0r = r0; if (r0r > LQ - 4) r0r = LQ - 4;   // clamp reads; stores guarded
  const unsigned int* qrow = qpk + ((size_t)(b * LQ + r0r)) * 32 + h * 8;
  unsigned int qw[4][8];   // wave-uniform packed f16 q -> SGPRs
  #pragma unroll
  for (int r = 0; r < 4; ++r) {
    #pragma unroll
    for (int i = 0; i < 8; ++i)
      qw[r][i] = bcastu(qrow[r * 32 + i]);
  }

  float lg[4][12];
  #pragma unroll
  for (int tt = 0; tt < 12; ++tt) {
    const int k = lane + (tt << 6);
    if (tt < 11 || k < LK) {
      float a0 = 0.f, a1 = 0.f, a2 = 0.f, a3 = 0.f;
      #pragma unroll
      for (int d4 = 0; d4 < 4; ++d4) {
        const uint2 w = KT2[d4 * PITCH + k];
        a0 = dot2(w.x, u2h(qw[0][2 * d4]), a0); a0 = dot2(w.y, u2h(qw[0][2 * d4 + 1]), a0);
        a1 = dot2(w.x, u2h(qw[1][2 * d4]), a1); a1 = dot2(w.y, u2h(qw[1][2 * d4 + 1]), a1);
        a2 = dot2(w.x, u2h(qw[2][2 * d4]), a2); a2 = dot2(w.y, u2h(qw[2][2 * d4 + 1]), a2);
        a3 = dot2(w.x, u2h(qw[3][2 * d4]), a3); a3 = dot2(w.y, u2h(qw[3][2 * d4 + 1]), a3);
      }
      lg[0][tt] = a0; lg[1][tt] = a1; lg[2][tt] = a2; lg[3][tt] = a3;
    } else {
      lg[0][tt] = -3.0e38f; lg[1][tt] = -3.0e38f;
      lg[2][tt] = -3.0e38f; lg[3][tt] = -3.0e38f;
    }
  }

  // per-lane heads (max of this lane's 12 keys) per row
  unsigned int hs[4];
  #pragma unroll
  for (int r = 0; r < 4; ++r) {
    float m = lg[r][0];
    #pragma unroll
    for (int tt = 1; tt < 12; ++tt) m = fmaxf(m, lg[r][tt]);
    hs[r] = f2sort(m);
  }

  // stage 1: sort heads descending -> L = exact 16th largest head
  sort64u_desc4(hs);
  unsigned int L[4];
  #pragma unroll
  for (int r = 0; r < 4; ++r) L[r] = __shfl(hs[r], 15);

  // stage 2: compact candidates (value u32 + key u16)
  int cb[4] = {0, 0, 0, 0};
  #pragma unroll
  for (int tt = 0; tt < 12; ++tt) {
    const int k = lane + (tt << 6);
    #pragma unroll
    for (int r = 0; r < 4; ++r) {
      const unsigned int s = f2sort(lg[r][tt]);
      const bool p = s >= L[r];
      const unsigned long long m = __ballot(p);
      if (p) {
        const int pos = cb[r] + (int)__popcll(m & below);
        if (pos < 64) { cV[r * 64 + pos] = s; cK[r * 64 + pos] = (unsigned short)k; }
      }
      cb[r] += (int)__popcll(m);
    }
  }

  // stage 3: sort candidate VALUES descending -> T@lane15, M@lane0
  unsigned int su[4], so[4];
  #pragma unroll
  for (int r = 0; r < 4; ++r) { su[r] = cV[r * 64 + lane]; so[r] = su[r]; }
  sort64u_desc4(so);
  unsigned int T[4]; float Mv[4];
  #pragma unroll
  for (int r = 0; r < 4; ++r) {
    T[r]  = __shfl(so[r], 15);
    Mv[r] = sort2f(__shfl(so[r], 0));
  }

  // kept set (value >= T; pads su==0 < T always); compact write, cap 24
  #pragma unroll
  for (int r = 0; r < 4; ++r) {
    const bool w = su[r] >= T[r];
    const unsigned long long mw = __ballot(w);
    if (w) {
      const int pos = (int)__popcll(mw & below);
      if (pos < 24) { sW[r * 24 + pos] = sort2f(su[r]); sK[r * 24 + pos] = cK[r * 64 + lane]; }
    }
  }

  // gather: 16 lanes per row (dd = dim), fixed 24 slots, fully unrolled
  const int dd = lane & 15;
  const int rsel = lane >> 4;
  const float ref = (rsel == 0) ? Mv[0] : (rsel == 1) ? Mv[1] : (rsel == 2) ? Mv[2] : Mv[3];
  const float* cwr = sW + rsel * 24;
  const unsigned short* cir = sK + rsel * 24;
  const float* vbase = vp + (size_t)(b * LK) * 64 + h * 16 + dd;
  float acc = 0.f, Z = 0.f;
  #pragma unroll
  for (int j = 0; j < 24; ++j) {
    const float e = __expf(cwr[j] - ref);
    Z += e;
    acc = fmaf(e, vbase[(size_t)cir[j] * 64], acc);
  }
  if (r0 + rsel < LQ)
    ao[((size_t)(b * LQ + r0 + rsel)) * 64 + h * 16 + dd] = acc / Z;
}

// ---------------------------------------------------------------------------
// FUSED cross-FFN + MGAN pre (layer 0). 16 rows/block, grid 750, 4
// rows/thread, coalesced direct-L2 weights, R12 unroll depths. qp output
// PACKED f16 (bit-identical: same packh2 awg would have run).
// ---------------------------------------------------------------------------
__global__ __launch_bounds__(256) void ffn_pre_kernel(
    const float* __restrict__ ao, const float* __restrict__ qres,
    const float* __restrict__ Wo,
    const float* __restrict__ g1, const float* __restrict__ b1n,
    const float* __restrict__ W1, const float* __restrict__ bb1,
    const float* __restrict__ W2, const float* __restrict__ bb2,
    const float* __restrict__ g2, const float* __restrict__ b2n,
    const float* __restrict__ lng, const float* __restrict__ lnb,
    const float* __restrict__ fc1W, const float* __restrict__ fc1b,
    const float* __restrict__ fc2W, const float* __restrict__ fc2b,
    const float* __restrict__ Wq,
    float* __restrict__ qn, float* __restrict__ sg,
    unsigned int* __restrict__ qp)
{
  __shared__ float xs[16][64];
  __shared__ float hsm[16][256];
  const int t = threadIdx.x, rr = t >> 6, cc = t & 63;
  const size_t base = (size_t)blockIdx.x * 16;
  for (int i = t; i < 1024; i += 256) xs[i >> 6][i & 63] = ao[base * 64 + i];
  __syncthreads();
  float acc[4];
  #pragma unroll
  for (int p = 0; p < 4; ++p) acc[p] = 0.f;
  #pragma unroll 8
  for (int c = 0; c < 64; ++c) {
    const float w = Wo[c * 64 + cc];
    #pragma unroll
    for (int p = 0; p < 4; ++p) acc[p] = fmaf(xs[p * 4 + rr][c], w, acc[p]);
  }
  #pragma unroll
  for (int p = 0; p < 4; ++p) acc[p] += qres[(base + p * 4 + rr) * 64 + cc];
  __syncthreads();
  float x1[4];
  #pragma unroll
  for (int p = 0; p < 4; ++p) {
    x1[p] = row_ln(acc[p], g1[cc], b1n[cc]);
    xs[p * 4 + rr][cc] = x1[p];
  }
  __syncthreads();
  {
    float hv[16];
    #pragma unroll
    for (int r = 0; r < 16; ++r) hv[r] = 0.f;
    #pragma unroll 4
    for (int c = 0; c < 64; ++c) {
      const float w = W1[c * 256 + t];
      #pragma unroll
      for (int r = 0; r < 16; ++r) hv[r] = fmaf(xs[r][c], w, hv[r]);
    }
    const float bb = bb1[t];
    #pragma unroll
    for (int r = 0; r < 16; ++r) hsm[r][t] = fmaxf(hv[r] + bb, 0.f);
  }
  __syncthreads();
  float acc2[4];
  #pragma unroll
  for (int p = 0; p < 4; ++p) acc2[p] = bb2[cc];
  #pragma unroll 8
  for (int c = 0; c < 256; ++c) {
    const float w = W2[c * 64 + cc];
    #pragma unroll
    for (int p = 0; p < 4; ++p) acc2[p] = fmaf(hsm[p * 4 + rr][c], w, acc2[p]);
  }
  // x = LN(ffn + x1); qn = LN(x) — xs reuse is safe: last xs read was
  // guarded by the post-W1 barrier above.
  float qv[4];
  #pragma unroll
  for (int p = 0; p < 4; ++p) {
    const float xv = row_ln(acc2[p] + x1[p], g2[cc], b2n[cc]);
    qv[p] = row_ln(xv, lng[cc], lnb[cc]);
    qn[(base + p * 4 + rr) * 64 + cc] = qv[p];
  }
  __syncthreads();
  #pragma unroll
  for (int p = 0; p < 4; ++p) xs[p * 4 + rr][cc] = qv[p];
  __syncthreads();
  float d1[4], d2[4];
  #pragma unroll
  for (int p = 0; p < 4; ++p) { d1[p] = fc1b[cc]; d2[p] = fc2b[cc]; }
  #pragma unroll 4
  for (int c = 0; c < 64; ++c) {
    const float w1 = fc1W[c * 64 + cc];
    const float w2 = fc2W[c * 64 + cc];
    #pragma unroll
    for (int p = 0; p < 4; ++p) {
      const float xq = xs[p * 4 + rr][c];
      d1[p] = fmaf(xq, w1, d1[p]);
      d2[p] = fmaf(xq, w2, d2[p]);
    }
  }
  float sv[4];
  #pragma unroll
  for (int p = 0; p < 4; ++p) {
    sv[p] = sigmoidf(d1[p]) * d2[p];
    sg[(base + p * 4 + rr) * 64 + cc] = sv[p];
  }
  __syncthreads();
  #pragma unroll
  for (int p = 0; p < 4; ++p) xs[p * 4 + rr][cc] = sv[p];
  __syncthreads();
  float aq[4];
  #pragma unroll
  for (int p = 0; p < 4; ++p) aq[p] = 0.f;
  #pragma unroll 8
  for (int c = 0; c < 64; ++c) {
    const float w = Wq[c * 64 + cc];
    #pragma unroll
    for (int p = 0; p < 4; ++p) aq[p] = fmaf(xs[p * 4 + rr][c], w, aq[p]);
  }
  #pragma unroll
  for (int p = 0; p < 4; ++p) {
    const float v0 = aq[p] * 0.25f;
    const float vN = __shfl_xor(v0, 1);   // partner dim (cc^1)
    if (!(cc & 1))
      qp[(base + p * 4 + rr) * 32 + (cc >> 1)] = packh2(v0, vN);
  }
}

// ---------------------------------------------------------------------------
// Fused awg_out(layer i) + mgan_pre(layer i+1): x never touches HBM.
// 16 rows/block, grid 750, 4 rows/thread, R12 unroll depths; qp packed.
// ---------------------------------------------------------------------------
__global__ __launch_bounds__(256) void out_pre_kernel(
    const float* __restrict__ ao, const float* __restrict__ sg,
    const float* __restrict__ qn, const float* __restrict__ Wo,
    const float* __restrict__ g_, const float* __restrict__ b_,
    const float* __restrict__ lng, const float* __restrict__ lnb,
    const float* __restrict__ W1, const float* __restrict__ bb1,
    const float* __restrict__ W2, const float* __restrict__ bb2,
    const float* __restrict__ Wq,
    float* __restrict__ qn_out, float* __restrict__ sg_out,
    unsigned int* __restrict__ qp_out)
{
  __shared__ float xs[16][64];
  const int t = threadIdx.x, rr = t >> 6, cc = t & 63;
  const size_t base = (size_t)blockIdx.x * 16;
  for (int i = t; i < 1024; i += 256) xs[i >> 6][i & 63] = ao[base * 64 + i];
  __syncthreads();
  float accp[4], sgv[4];
  #pragma unroll
  for (int p = 0; p < 4; ++p) accp[p] = 0.f;
  #pragma unroll 8
  for (int c = 0; c < 64; ++c) {
    const float w = Wo[c * 64 + cc];
    #pragma unroll
    for (int p = 0; p < 4; ++p) accp[p] = fmaf(xs[p * 4 + rr][c], w, accp[p]);
  }
  #pragma unroll
  for (int p = 0; p < 4; ++p) {
    sgv[p] = sg[(base + p * 4 + rr) * 64 + cc];
    accp[p] += sgv[p];
  }
  __syncthreads();
  float qv[4];
  #pragma unroll
  for (int p = 0; p < 4; ++p) {
    const size_t idx = (base + p * 4 + rr) * 64 + cc;
    const float awg = row_ln(accp[p], g_[cc], b_[cc]);
    const float xv = qn[idx] + sgv[p] * sigmoidf(awg);
    qv[p] = row_ln(xv, lng[cc], lnb[cc]);
    qn_out[idx] = qv[p];
    xs[p * 4 + rr][cc] = qv[p];
  }
  __syncthreads();
  float d1[4], d2[4];
  #pragma unroll
  for (int p = 0; p < 4; ++p) { d1[p] = bb1[cc]; d2[p] = bb2[cc]; }
  #pragma unroll 4
  for (int c = 0; c < 64; ++c) {
    const float w1 = W1[c * 64 + cc];
    const float w2 = W2[c * 64 + cc];
    #pragma unroll
    for (int p = 0; p < 4; ++p) {
      const float xv = xs[p * 4 + rr][c];
      d1[p] = fmaf(xv, w1, d1[p]);
      d2[p] = fmaf(xv, w2, d2[p]);
    }
  }
  __syncthreads();
  float sv[4];
  #pragma unroll
  for (int p = 0; p < 4; ++p) {
    sv[p] = sigmoidf(d1[p]) * d2[p];
    sg_out[(base + p * 4 + rr) * 64 + cc] = sv[p];
    xs[p * 4 + rr][cc] = sv[p];
  }
  __syncthreads();
  float aq[4];
  #pragma unroll
  for (int p = 0; p < 4; ++p) aq[p] = 0.f;
  #pragma unroll 8
  for (int c = 0; c < 64; ++c) {
    const float w = Wq[c * 64 + cc];
    #pragma unroll
    for (int p = 0; p < 4; ++p) aq[p] = fmaf(xs[p * 4 + rr][c], w, aq[p]);
  }
  #pragma unroll
  for (int p = 0; p < 4; ++p) {
    const float v0 = aq[p] * 0.25f;
    const float vN = __shfl_xor(v0, 1);   // partner dim (cc^1)
    if (!(cc & 1))
      qp_out[(base + p * 4 + rr) * 32 + (cc >> 1)] = packh2(v0, vN);
  }
}

// ---------------------------------------------------------------------------
// Fused awg_out(layer 1) + head: out = sigmoid(x2 @ fcW + fcb).
// 16 rows/block, grid 750, 4 rows/thread, R12 unroll depth.
// ---------------------------------------------------------------------------
__global__ __launch_bounds__(256) void out_final_kernel(
    const float* __restrict__ ao, const float* __restrict__ sg,
    const float* __restrict__ qn, const float* __restrict__ Wo,
    const float* __restrict__ g_, const float* __restrict__ b_,
    const float* __restrict__ fw, const float* __restrict__ fb,
    float* __restrict__ out)
{
  __shared__ float xs[16][64];
  const int t = threadIdx.x, rr = t >> 6, cc = t & 63;
  const size_t base = (size_t)blockIdx.x * 16;
  for (int i = t; i < 1024; i += 256) xs[i >> 6][i & 63] = ao[base * 64 + i];
  __syncthreads();
  float accp[4];
  #pragma unroll
  for (int p = 0; p < 4; ++p) accp[p] = 0.f;
  #pragma unroll 8
  for (int c = 0; c < 64; ++c) {
    const float w = Wo[c * 64 + cc];
    #pragma unroll
    for (int p = 0; p < 4; ++p) accp[p] = fmaf(xs[p * 4 + rr][c], w, accp[p]);
  }
  #pragma unroll
  for (int p = 0; p < 4; ++p) {
    const size_t idx = (base + p * 4 + rr) * 64 + cc;
    const float sgv = sg[idx];
    const float a = accp[p] + sgv;
    const float awg = row_ln(a, g_[cc], b_[cc]);
    const float xv = qn[idx] + sgv * sigmoidf(awg);
    float v = xv * fw[cc];
    #pragma unroll
    for (int off = 32; off > 0; off >>= 1) v += __shfl_xor(v, off);
    if (cc == 0) out[base + p * 4 + rr] = sigmoidf(v + fb[0]);
  }
}

// ---------------------------------------------------------------------------
extern "C" void kernel_launch(void* const* d_in, const int* in_sizes, int n_in,
                              void* d_out, int out_size, void* d_ws, size_t ws_size,
                              hipStream_t stream) {
  (void)in_sizes; (void)n_in; (void)out_size; (void)ws_size;

  const float* q     = (const float*)d_in[0];
  const float* enc   = (const float*)d_in[1];
  const float* calWq = (const float*)d_in[2];
  const float* calWk = (const float*)d_in[3];
  const float* calWv = (const float*)d_in[4];
  const float* calWo = (const float*)d_in[5];
  const float* ln1g  = (const float*)d_in[6];
  const float* ln1b  = (const float*)d_in[7];
  const float* W1    = (const float*)d_in[8];
  const float* b1v   = (const float*)d_in[9];
  const float* W2    = (const float*)d_in[10];
  const float* b2v   = (const float*)d_in[11];
  const float* ln2g  = (const float*)d_in[12];
  const float* ln2b  = (const float*)d_in[13];
  const float* mlng  = (const float*)d_in[14];
  const float* mlnb  = (const float*)d_in[15];
  const float* mfc1W = (const float*)d_in[16];
  const float* mfc1b = (const float*)d_in[17];
  const float* mfc2W = (const float*)d_in[18];
  const float* mfc2b = (const float*)d_in[19];
  const float* mWq   = (const float*)d_in[20];
  const float* mWk   = (const float*)d_in[21];
  const float* mWv   = (const float*)d_in[22];
  const float* mWo   = (const float*)d_in[23];
  const float* malng = (const float*)d_in[24];
  const float* malnb = (const float*)d_in[25];
  const float* fcW   = (const float*)d_in[26];
  const float* fcb   = (const float*)d_in[27];
  float* out = (float*)d_out;

  float* ws  = (float*)d_ws;
  float* kv  = ws + WS_KV;
  float* qp  = ws + WS_QP;
  float* aob = ws + WS_AO;
  float* qnb = ws + WS_QN;
  float* sgb = ws + WS_SG;

  const size_t crossLds = (750 * 18 + 16 * 754 + 4 * 288) * 2;        // 53,432 B
  const size_t awgLds   = 4 * PITCH * 8 + 8192 + 4096 + 3072 + 1536;  // 40,928 B

  // 1) all K/V projections + cross q-projection in one dispatch
  //    (K slabs y==0/2/4 stored packed f16; V slabs f32)
  kvq_proj_kernel<<<dim3(750, 7), 256, 0, stream>>>(enc, q, calWq, calWk, calWv,
                                                    mWk, mWv, kv, qp);

  // 2) cross attention (MFMA flash-lite, pre-packed K) + fused FFN+MGAN-pre
  cross_attn_kernel<<<dim3(47, NH_, B_), 256, crossLds, stream>>>(
      qp, (const unsigned int*)kv, kv + 192000, aob);
  ffn_pre_kernel<<<750, 256, 0, stream>>>(aob, q, calWo, ln1g, ln1b,
                                          W1, b1v, W2, b2v, ln2g, ln2b,
                                          mlng, mlnb, mfc1W, mfc1b,
                                          mfc2W, mfc2b, mWq, qnb, sgb,
                                          (unsigned int*)qp);

  // 3) MGAN layer 0 attention + fused out/pre
  awg_attn_kernel<<<dim3(94, NH_, B_), 512, awgLds, stream>>>(
      (const unsigned int*)qp, (const unsigned int*)(kv + 2 * 192000),
      kv + 3 * 192000, aob);
  out_pre_kernel<<<750, 256, 0, stream>>>(aob, sgb, qnb, mWo, malng, malnb,
                                          mlng + 64, mlnb + 64,
                                          mfc1W + 4096, mfc1b + 64,
                                          mfc2W + 4096, mfc2b + 64,
                                          mWq + 4096, qnb, sgb,
                                          (unsigned int*)qp);

  // 4) MGAN layer 1 + head
  awg_attn_kernel<<<dim3(94, NH_, B_), 512, awgLds, stream>>>(
      (const unsigned int*)qp, (const unsigned int*)(kv + 4 * 192000),
      kv + 5 * 192000, aob);
  out_final_kernel<<<750, 256, 0, stream>>>(aob, sgb, qnb, mWo + 4096,
                                            malng + 64, malnb + 64, fcW, fcb, out);
}

// Round 15
// 311.154 us; speedup vs baseline: 1.2026x; 1.0160x over previous
//
#include <hip/hip_runtime.h>
#include <hip/hip_bf16.h>

using bf16 = __hip_bfloat16;

#define DEV_INLINE __device__ __forceinline__

// Problem constants
constexpr int B_  = 4;
constexpr int LQ  = 3000;
constexpr int LK  = 750;
constexpr int NH_ = 4;
constexpr float EPSF = 1e-6f;

// LDS pitch in uint2 elements per d4-row (>=750, odd) — awg kernel.
constexpr int PITCH = 751;

// Workspace layout (fp32 elements).
constexpr size_t WS_KV = 0;        // 6 x B*LK*64 = 1,152,000
constexpr size_t WS_XB = 1152000;  // B*LQ*64 = 768,000 (unused)
constexpr size_t WS_QP = 1920000;  // 768,000 (cal qp f32; later mgan qp packed f16)
constexpr size_t WS_AO = 2688000;  // 768,000
constexpr size_t WS_QN = 3456000;  // 768,000
constexpr size_t WS_SG = 4224000;  // 768,000

typedef _Float16 half2_t __attribute__((ext_vector_type(2)));
typedef _Float16 half4_t __attribute__((ext_vector_type(4)));
typedef float    f32x4   __attribute__((ext_vector_type(4)));

// correct gfx950 spelling (per compiler diagnostic r14): ...16x16x16f16
#define MFMA16(a, b, c) __builtin_amdgcn_mfma_f32_16x16x16f16((a), (b), (c), 0, 0, 0)

DEV_INLINE float sigmoidf(float x) { return 1.f / (1.f + __expf(-x)); }

DEV_INLINE unsigned int packh2(float a, float b) {
  half2_t h = { (_Float16)a, (_Float16)b };
  unsigned int u; __builtin_memcpy(&u, &h, 4); return u;
}
DEV_INLINE half2_t u2h(unsigned int u) {
  half2_t h; __builtin_memcpy(&h, &u, 4); return h;
}
DEV_INLINE unsigned short f2h(float f) {
  _Float16 h = (_Float16)f;
  unsigned short u; __builtin_memcpy(&u, &h, 2); return u;
}
// half4 from two 4-byte-aligned uints at p, p+2 (f16 units)
DEV_INLINE half4_t h4_from(const unsigned short* p) {
  unsigned int lo = *(const unsigned int*)p;
  unsigned int hi = *(const unsigned int*)(p + 2);
  unsigned long long v = ((unsigned long long)hi << 32) | lo;
  half4_t h; __builtin_memcpy(&h, &v, 8); return h;
}
// one v_dot2_f32_f16: acc + k.x*q.x + k.y*q.y
DEV_INLINE float dot2(unsigned int kw, half2_t qh, float acc) {
  return __builtin_amdgcn_fdot2(u2h(kw), qh, acc, false);
}

DEV_INLINE unsigned int f2sort(float f) {
  int ib = __float_as_int(f);
  return (unsigned int)(ib ^ ((ib >> 31) | 0x80000000));
}
// inverse of f2sort
DEV_INLINE float sort2f(unsigned int u) {
  const int ib = (u & 0x80000000u) ? (int)(u ^ 0x80000000u) : (int)~u;
  return __int_as_float(ib);
}

DEV_INLINE unsigned int bcastu(unsigned int v) {
  return (unsigned int)__builtin_amdgcn_readfirstlane((int)v);
}

// 4 independent descending bitonic sorts (one value/lane each) across the
// 64-lane wave — DPP/permute + VALU, ILP-4 by construction.
DEV_INLINE void sort64u_desc4(unsigned int v[4]) {
  const int lane = threadIdx.x & 63;
  #pragma unroll
  for (int k = 2; k <= 64; k <<= 1) {
    #pragma unroll
    for (int j = k >> 1; j > 0; j >>= 1) {
      const bool takeMax = ((lane & j) == 0) == ((lane & k) == 0);
      #pragma unroll
      for (int r = 0; r < 4; ++r) {
        const unsigned int o = __shfl_xor(v[r], j);
        v[r] = (takeMax == (v[r] > o)) ? v[r] : o;
      }
    }
  }
}

DEV_INLINE float row_ln(float v, float g, float b) {
  float s1 = v, s2 = v * v;
  #pragma unroll
  for (int off = 32; off > 0; off >>= 1) {
    s1 += __shfl_xor(s1, off);
    s2 += __shfl_xor(s2, off);
  }
  const float m   = s1 * (1.f / 64.f);
  const float var = s2 * (1.f / 64.f) - m * m;
  return (v - m) * rsqrtf(var + EPSF) * g + b;
}

// ---------------------------------------------------------------------------
// Merged projections: y<6 -> K/V of enc (188 blocks used); y==6 -> q-proj
// (750 blocks). 16 rows/block, 4 rows/thread, coalesced direct-L2 weights,
// R12 unroll depth. R15: y==1 (cal V) joins the PACKED-f16 path — cal V
// feeds only cross_attn (mgan V y==3/5 stay f32 for awg's gather).
// All packs bit-identical (same packh2 of the same acc).
// ---------------------------------------------------------------------------
__global__ __launch_bounds__(256) void kvq_proj_kernel(
    const float* __restrict__ enc, const float* __restrict__ q,
    const float* __restrict__ calWq,
    const float* __restrict__ calWk, const float* __restrict__ calWv,
    const float* __restrict__ mWk, const float* __restrict__ mWv,
    float* __restrict__ kv, float* __restrict__ qp)
{
  const int y = blockIdx.y;
  if (y < 6 && blockIdx.x >= 188) return;
  __shared__ __align__(16) float xs[16][64];
  const int t = threadIdx.x, rr = t >> 6, cc = t & 63;
  const float* W;
  const float* src;
  float* dst;
  float scale = 1.f;
  int nrows = 3000;
  switch (y) {
    case 0: W = calWk; src = enc; dst = kv;               break;
    case 1: W = calWv; src = enc; dst = kv + 192000;      break;
    case 2: W = mWk;        src = enc; dst = kv + 384000; break;
    case 3: W = mWv;        src = enc; dst = kv + 576000; break;
    case 4: W = mWk + 4096; src = enc; dst = kv + 768000; break;
    case 5: W = mWv + 4096; src = enc; dst = kv + 960000; break;
    default: W = calWq; src = q; dst = qp; scale = 0.25f; nrows = 12000; break;
  }
  const bool packK = (y == 0) || (y == 1) || (y == 2) || (y == 4);
  const int base = blockIdx.x * 16;
  {
    const int grow = base + (t >> 4);
    float4 v = {0.f, 0.f, 0.f, 0.f};
    if (grow < nrows) v = *(const float4*)&src[(size_t)grow * 64 + (t & 15) * 4];
    ((float4*)xs)[t] = v;
  }
  __syncthreads();
  float acc[4] = {0.f, 0.f, 0.f, 0.f};
  #pragma unroll 8
  for (int c = 0; c < 64; ++c) {
    const float w = W[c * 64 + cc];
    #pragma unroll
    for (int p = 0; p < 4; ++p) acc[p] = fmaf(xs[p * 4 + rr][c], w, acc[p]);
  }
  #pragma unroll
  for (int p = 0; p < 4; ++p) {
    const int grow = base + p * 4 + rr;
    if (packK) {
      const float accN = __shfl_xor(acc[p], 1);   // partner dim (cc^1)
      if (!(cc & 1) && grow < nrows)
        ((unsigned int*)dst)[(size_t)grow * 32 + (cc >> 1)] = packh2(acc[p], accN);
    } else if (grow < nrows) {
      dst[(size_t)grow * 64 + cc] = acc[p] * scale;
    }
  }
}

// ---------------------------------------------------------------------------
// CROSS attention via MFMA (flash-lite, no max subtraction — logits bounded).
// grid (47, NH, B), block 256 (4 waves); wave owns 16 q-rows (block: 64).
// K AND V arrive PRE-PACKED f16 — staging is pure copy + 16-bit extracts
// (no converts), half the K/V fetch bytes.
// ---------------------------------------------------------------------------
__global__ __launch_bounds__(256) void cross_attn_kernel(
    const float* __restrict__ qp, const unsigned int* __restrict__ kp,
    const unsigned int* __restrict__ vp, float* __restrict__ ao)
{
  extern __shared__ char smem[];
  unsigned short* Kl = (unsigned short*)smem;       // [750][18]
  unsigned short* Vt = Kl + 750 * 18;               // [16][754]
  unsigned short* Pt = Vt + 16 * 754;               // [4 waves][16][18]

  const int t = threadIdx.x;
  const int h = blockIdx.y, b = blockIdx.z;
  const unsigned int* kslab = kp + ((size_t)(b * LK)) * 32 + h * 8;  // u32 units
  const unsigned int* vslab = vp + ((size_t)(b * LK)) * 32 + h * 8;  // u32 units

  // stage K (pre-packed f16, pitch 18) and V transposed ([d][key])
  for (int k = t; k < LK; k += 256) {
    const uint4* ks = (const uint4*)(kslab + (size_t)k * 32);
    const uint4* vs = (const uint4*)(vslab + (size_t)k * 32);
    unsigned int* kr = (unsigned int*)(Kl + k * 18);
    const uint4 a0 = ks[0], a1 = ks[1];
    kr[0] = a0.x; kr[1] = a0.y; kr[2] = a0.z; kr[3] = a0.w;
    kr[4] = a1.x; kr[5] = a1.y; kr[6] = a1.z; kr[7] = a1.w;
    const uint4 b0 = vs[0], b1 = vs[1];
    const unsigned int vv[8] = {b0.x, b0.y, b0.z, b0.w, b1.x, b1.y, b1.z, b1.w};
    #pragma unroll
    for (int j = 0; j < 8; ++j) {
      Vt[(2 * j + 0) * 754 + k] = (unsigned short)(vv[j] & 0xFFFFu);
      Vt[(2 * j + 1) * 754 + k] = (unsigned short)(vv[j] >> 16);
    }
  }
  // zero V pad keys 750..751 (P is masked there, but 0*NaN would poison O)
  if (t < 32) Vt[(t & 15) * 754 + 750 + (t >> 4)] = 0;
  __syncthreads();

  const int wave = t >> 6, lane = t & 63;
  const int col = lane & 15, quad = lane >> 4;
  const int qbase = blockIdx.x * 64 + wave * 16;
  unsigned short* Pt_w = Pt + wave * 288;   // [16][18]

  // Q A-fragment: A[m=col][k=quad*4+j], constant across tiles
  int qrow = qbase + col; if (qrow >= LQ) qrow = LQ - 1;
  const float* qptr = qp + ((size_t)(b * LQ + qrow)) * 64 + h * 16 + quad * 4;
  half4_t aQ;
  {
    unsigned long long v = ((unsigned long long)packh2(qptr[2], qptr[3]) << 32)
                         | packh2(qptr[0], qptr[1]);
    __builtin_memcpy(&aQ, &v, 8);
  }

  f32x4 O = {0.f, 0.f, 0.f, 0.f};
  float Zp[4] = {0.f, 0.f, 0.f, 0.f};
  const f32x4 zeroC = {0.f, 0.f, 0.f, 0.f};

  for (int tile = 0; tile < 47; ++tile) {
    const int key = tile * 16 + col;
    // B-fragment K^T: B[k=quad*4+j][n=col] = K[key=n][k]
    const half4_t bK = h4_from(Kl + key * 18 + quad * 4);
    f32x4 S = MFMA16(aQ, bK, zeroC);
    // exp + mask (C layout: col=lane&15 -> key, row=quad*4+r)
    const bool valid = key < LK;
    float e0 = valid ? __expf(S[0]) : 0.f;
    float e1 = valid ? __expf(S[1]) : 0.f;
    float e2 = valid ? __expf(S[2]) : 0.f;
    float e3 = valid ? __expf(S[3]) : 0.f;
    Zp[0] += e0; Zp[1] += e1; Zp[2] += e2; Zp[3] += e3;
    // C->A transpose through wave-private LDS tile (barrier-free)
    Pt_w[(quad * 4 + 0) * 18 + col] = f2h(e0);
    Pt_w[(quad * 4 + 1) * 18 + col] = f2h(e1);
    Pt_w[(quad * 4 + 2) * 18 + col] = f2h(e2);
    Pt_w[(quad * 4 + 3) * 18 + col] = f2h(e3);
    const half4_t aP = h4_from(Pt_w + col * 18 + quad * 4);
    // B-fragment V: B[k=quad*4+j][n=col] = V[key=tile*16+quad*4+j][d=col]
    const half4_t bV = h4_from(Vt + col * 754 + tile * 16 + quad * 4);
    O = MFMA16(aP, bV, O);
  }

  // reduce Z across the 16-lane col group (rows quad*4+r live there)
  #pragma unroll
  for (int r = 0; r < 4; ++r) {
    float z = Zp[r];
    z += __shfl_xor(z, 1);
    z += __shfl_xor(z, 2);
    z += __shfl_xor(z, 4);
    z += __shfl_xor(z, 8);
    Zp[r] = z;
  }

  #pragma unroll
  for (int r = 0; r < 4; ++r) {
    const int orow = qbase + quad * 4 + r;
    if (orow < LQ)
      ao[((size_t)(b * LQ + orow)) * 64 + h * 16 + col] = O[r] / Zp[r];
  }
}

// ---------------------------------------------------------------------------
// AWG attention v5.1. grid (94, NH, B), block 512 (8 waves, 4 q-rows/wave).
// q arrives PRE-PACKED f16 (u32 pairs) — 8 loads/row, same bits.
// Selection machinery unchanged (proven core, 55.0 µs measured).
// ---------------------------------------------------------------------------
__global__ __launch_bounds__(512) void awg_attn_kernel(
    const unsigned int* __restrict__ qpk, const unsigned int* __restrict__ kp,
    const float* __restrict__ vp, float* __restrict__ ao)
{
  extern __shared__ char smem[];
  uint2*          KT2   = (uint2*)smem;                                      // [4][PITCH] = 24,032 B
  unsigned int*   candV = (unsigned int*)(smem + 4 * PITCH * 8);             // [8][4][64] = 8,192
  unsigned short* candK = (unsigned short*)(smem + 4 * PITCH * 8 + 8192);    // [8][4][64] = 4,096
  float*          selW  = (float*)(smem + 4 * PITCH * 8 + 8192 + 4096);      // [8][4][24] = 3,072
  unsigned short* selK  = (unsigned short*)(smem + 4 * PITCH * 8 + 8192 + 4096 + 3072); // 1,536

  const int t = threadIdx.x;
  const int h = blockIdx.y, b = blockIdx.z;
  const unsigned int* kslab = kp + ((size_t)(b * LK)) * 32 + h * 8;

  for (int k = t; k < LK; k += 512) {
    const uint2* ks = (const uint2*)(kslab + (size_t)k * 32);
    #pragma unroll
    for (int d4 = 0; d4 < 4; ++d4) KT2[d4 * PITCH + k] = ks[d4];
  }
  __syncthreads();

  const int wave = t >> 6, lane = t & 63;
  const unsigned long long below = (1ull << lane) - 1ull;
  unsigned int*   cV = candV + wave * 256;
  unsigned short* cK = candK + wave * 256;
  float*          sW = selW + wave * 96;
  unsigned short* sK = selK + wave * 96;

  // pad select arrays (wave-private; unwritten tail -> exp()==0 in gather)
  sW[lane] = -3.0e38f; sK[lane] = 0;
  if (lane < 32) { sW[64 + lane] = -3.0e38f; sK[64 + lane] = 0; }
  // zero candidate values (pads sort to the tail and never pass >= T)
  #pragma unroll
  for (int r = 0; r < 4; ++r) cV[r * 64 + lane] = 0u;

  const int r0 = blockIdx.x * 32 + wave * 4;
  int r0r = r0; if (r0r > LQ - 4) r0r = LQ - 4;   // clamp reads; stores guarded
  const unsigned int* qrow = qpk + ((size_t)(b * LQ + r0r)) * 32 + h * 8;
  unsigned int qw[4][8];   // wave-uniform packed f16 q -> SGPRs
  #pragma unroll
  for (int r = 0; r < 4; ++r) {
    #pragma unroll
    for (int i = 0; i < 8; ++i)
      qw[r][i] = bcastu(qrow[r * 32 + i]);
  }

  float lg[4][12];
  #pragma unroll
  for (int tt = 0; tt < 12; ++tt) {
    const int k = lane + (tt << 6);
    if (tt < 11 || k < LK) {
      float a0 = 0.f, a1 = 0.f, a2 = 0.f, a3 = 0.f;
      #pragma unroll
      for (int d4 = 0; d4 < 4; ++d4) {
        const uint2 w = KT2[d4 * PITCH + k];
        a0 = dot2(w.x, u2h(qw[0][2 * d4]), a0); a0 = dot2(w.y, u2h(qw[0][2 * d4 + 1]), a0);
        a1 = dot2(w.x, u2h(qw[1][2 * d4]), a1); a1 = dot2(w.y, u2h(qw[1][2 * d4 + 1]), a1);
        a2 = dot2(w.x, u2h(qw[2][2 * d4]), a2); a2 = dot2(w.y, u2h(qw[2][2 * d4 + 1]), a2);
        a3 = dot2(w.x, u2h(qw[3][2 * d4]), a3); a3 = dot2(w.y, u2h(qw[3][2 * d4 + 1]), a3);
      }
      lg[0][tt] = a0; lg[1][tt] = a1; lg[2][tt] = a2; lg[3][tt] = a3;
    } else {
      lg[0][tt] = -3.0e38f; lg[1][tt] = -3.0e38f;
      lg[2][tt] = -3.0e38f; lg[3][tt] = -3.0e38f;
    }
  }

  // per-lane heads (max of this lane's 12 keys) per row
  unsigned int hs[4];
  #pragma unroll
  for (int r = 0; r < 4; ++r) {
    float m = lg[r][0];
    #pragma unroll
    for (int tt = 1; tt < 12; ++tt) m = fmaxf(m, lg[r][tt]);
    hs[r] = f2sort(m);
  }

  // stage 1: sort heads descending -> L = exact 16th largest head
  sort64u_desc4(hs);
  unsigned int L[4];
  #pragma unroll
  for (int r = 0; r < 4; ++r) L[r] = __shfl(hs[r], 15);

  // stage 2: compact candidates (value u32 + key u16)
  int cb[4] = {0, 0, 0, 0};
  #pragma unroll
  for (int tt = 0; tt < 12; ++tt) {
    const int k = lane + (tt << 6);
    #pragma unroll
    for (int r = 0; r < 4; ++r) {
      const unsigned int s = f2sort(lg[r][tt]);
      const bool p = s >= L[r];
      const unsigned long long m = __ballot(p);
      if (p) {
        const int pos = cb[r] + (int)__popcll(m & below);
        if (pos < 64) { cV[r * 64 + pos] = s; cK[r * 64 + pos] = (unsigned short)k; }
      }
      cb[r] += (int)__popcll(m);
    }
  }

  // stage 3: sort candidate VALUES descending -> T@lane15, M@lane0
  unsigned int su[4], so[4];
  #pragma unroll
  for (int r = 0; r < 4; ++r) { su[r] = cV[r * 64 + lane]; so[r] = su[r]; }
  sort64u_desc4(so);
  unsigned int T[4]; float Mv[4];
  #pragma unroll
  for (int r = 0; r < 4; ++r) {
    T[r]  = __shfl(so[r], 15);
    Mv[r] = sort2f(__shfl(so[r], 0));
  }

  // kept set (value >= T; pads su==0 < T always); compact write, cap 24
  #pragma unroll
  for (int r = 0; r < 4; ++r) {
    const bool w = su[r] >= T[r];
    const unsigned long long mw = __ballot(w);
    if (w) {
      const int pos = (int)__popcll(mw & below);
      if (pos < 24) { sW[r * 24 + pos] = sort2f(su[r]); sK[r * 24 + pos] = cK[r * 64 + lane]; }
    }
  }

  // gather: 16 lanes per row (dd = dim), fixed 24 slots, fully unrolled
  const int dd = lane & 15;
  const int rsel = lane >> 4;
  const float ref = (rsel == 0) ? Mv[0] : (rsel == 1) ? Mv[1] : (rsel == 2) ? Mv[2] : Mv[3];
  const float* cwr = sW + rsel * 24;
  const unsigned short* cir = sK + rsel * 24;
  const float* vbase = vp + (size_t)(b * LK) * 64 + h * 16 + dd;
  float acc = 0.f, Z = 0.f;
  #pragma unroll
  for (int j = 0; j < 24; ++j) {
    const float e = __expf(cwr[j] - ref);
    Z += e;
    acc = fmaf(e, vbase[(size_t)cir[j] * 64], acc);
  }
  if (r0 + rsel < LQ)
    ao[((size_t)(b * LQ + r0 + rsel)) * 64 + h * 16 + dd] = acc / Z;
}

// ---------------------------------------------------------------------------
// FUSED cross-FFN + MGAN pre (layer 0). 16 rows/block, grid 750, 4
// rows/thread, coalesced direct-L2 weights, R12 unroll depths. qp output
// PACKED f16 (bit-identical: same packh2 awg would have run).
// ---------------------------------------------------------------------------
__global__ __launch_bounds__(256) void ffn_pre_kernel(
    const float* __restrict__ ao, const float* __restrict__ qres,
    const float* __restrict__ Wo,
    const float* __restrict__ g1, const float* __restrict__ b1n,
    const float* __restrict__ W1, const float* __restrict__ bb1,
    const float* __restrict__ W2, const float* __restrict__ bb2,
    const float* __restrict__ g2, const float* __restrict__ b2n,
    const float* __restrict__ lng, const float* __restrict__ lnb,
    const float* __restrict__ fc1W, const float* __restrict__ fc1b,
    const float* __restrict__ fc2W, const float* __restrict__ fc2b,
    const float* __restrict__ Wq,
    float* __restrict__ qn, float* __restrict__ sg,
    unsigned int* __restrict__ qp)
{
  __shared__ float xs[16][64];
  __shared__ float hsm[16][256];
  const int t = threadIdx.x, rr = t >> 6, cc = t & 63;
  const size_t base = (size_t)blockIdx.x * 16;
  for (int i = t; i < 1024; i += 256) xs[i >> 6][i & 63] = ao[base * 64 + i];
  __syncthreads();
  float acc[4];
  #pragma unroll
  for (int p = 0; p < 4; ++p) acc[p] = 0.f;
  #pragma unroll 8
  for (int c = 0; c < 64; ++c) {
    const float w = Wo[c * 64 + cc];
    #pragma unroll
    for (int p = 0; p < 4; ++p) acc[p] = fmaf(xs[p * 4 + rr][c], w, acc[p]);
  }
  #pragma unroll
  for (int p = 0; p < 4; ++p) acc[p] += qres[(base + p * 4 + rr) * 64 + cc];
  __syncthreads();
  float x1[4];
  #pragma unroll
  for (int p = 0; p < 4; ++p) {
    x1[p] = row_ln(acc[p], g1[cc], b1n[cc]);
    xs[p * 4 + rr][cc] = x1[p];
  }
  __syncthreads();
  {
    float hv[16];
    #pragma unroll
    for (int r = 0; r < 16; ++r) hv[r] = 0.f;
    #pragma unroll 4
    for (int c = 0; c < 64; ++c) {
      const float w = W1[c * 256 + t];
      #pragma unroll
      for (int r = 0; r < 16; ++r) hv[r] = fmaf(xs[r][c], w, hv[r]);
    }
    const float bb = bb1[t];
    #pragma unroll
    for (int r = 0; r < 16; ++r) hsm[r][t] = fmaxf(hv[r] + bb, 0.f);
  }
  __syncthreads();
  float acc2[4];
  #pragma unroll
  for (int p = 0; p < 4; ++p) acc2[p] = bb2[cc];
  #pragma unroll 8
  for (int c = 0; c < 256; ++c) {
    const float w = W2[c * 64 + cc];
    #pragma unroll
    for (int p = 0; p < 4; ++p) acc2[p] = fmaf(hsm[p * 4 + rr][c], w, acc2[p]);
  }
  // x = LN(ffn + x1); qn = LN(x) — xs reuse is safe: last xs read was
  // guarded by the post-W1 barrier above.
  float qv[4];
  #pragma unroll
  for (int p = 0; p < 4; ++p) {
    const float xv = row_ln(acc2[p] + x1[p], g2[cc], b2n[cc]);
    qv[p] = row_ln(xv, lng[cc], lnb[cc]);
    qn[(base + p * 4 + rr) * 64 + cc] = qv[p];
  }
  __syncthreads();
  #pragma unroll
  for (int p = 0; p < 4; ++p) xs[p * 4 + rr][cc] = qv[p];
  __syncthreads();
  float d1[4], d2[4];
  #pragma unroll
  for (int p = 0; p < 4; ++p) { d1[p] = fc1b[cc]; d2[p] = fc2b[cc]; }
  #pragma unroll 4
  for (int c = 0; c < 64; ++c) {
    const float w1 = fc1W[c * 64 + cc];
    const float w2 = fc2W[c * 64 + cc];
    #pragma unroll
    for (int p = 0; p < 4; ++p) {
      const float xq = xs[p * 4 + rr][c];
      d1[p] = fmaf(xq, w1, d1[p]);
      d2[p] = fmaf(xq, w2, d2[p]);
    }
  }
  float sv[4];
  #pragma unroll
  for (int p = 0; p < 4; ++p) {
    sv[p] = sigmoidf(d1[p]) * d2[p];
    sg[(base + p * 4 + rr) * 64 + cc] = sv[p];
  }
  __syncthreads();
  #pragma unroll
  for (int p = 0; p < 4; ++p) xs[p * 4 + rr][cc] = sv[p];
  __syncthreads();
  float aq[4];
  #pragma unroll
  for (int p = 0; p < 4; ++p) aq[p] = 0.f;
  #pragma unroll 8
  for (int c = 0; c < 64; ++c) {
    const float w = Wq[c * 64 + cc];
    #pragma unroll
    for (int p = 0; p < 4; ++p) aq[p] = fmaf(xs[p * 4 + rr][c], w, aq[p]);
  }
  #pragma unroll
  for (int p = 0; p < 4; ++p) {
    const float v0 = aq[p] * 0.25f;
    const float vN = __shfl_xor(v0, 1);   // partner dim (cc^1)
    if (!(cc & 1))
      qp[(base + p * 4 + rr) * 32 + (cc >> 1)] = packh2(v0, vN);
  }
}

// ---------------------------------------------------------------------------
// Fused awg_out(layer i) + mgan_pre(layer i+1): x never touches HBM.
// 16 rows/block, grid 750, 4 rows/thread, R12 unroll depths; qp packed.
// ---------------------------------------------------------------------------
__global__ __launch_bounds__(256) void out_pre_kernel(
    const float* __restrict__ ao, const float* __restrict__ sg,
    const float* __restrict__ qn, const float* __restrict__ Wo,
    const float* __restrict__ g_, const float* __restrict__ b_,
    const float* __restrict__ lng, const float* __restrict__ lnb,
    const float* __restrict__ W1, const float* __restrict__ bb1,
    const float* __restrict__ W2, const float* __restrict__ bb2,
    const float* __restrict__ Wq,
    float* __restrict__ qn_out, float* __restrict__ sg_out,
    unsigned int* __restrict__ qp_out)
{
  __shared__ float xs[16][64];
  const int t = threadIdx.x, rr = t >> 6, cc = t & 63;
  const size_t base = (size_t)blockIdx.x * 16;
  for (int i = t; i < 1024; i += 256) xs[i >> 6][i & 63] = ao[base * 64 + i];
  __syncthreads();
  float accp[4], sgv[4];
  #pragma unroll
  for (int p = 0; p < 4; ++p) accp[p] = 0.f;
  #pragma unroll 8
  for (int c = 0; c < 64; ++c) {
    const float w = Wo[c * 64 + cc];
    #pragma unroll
    for (int p = 0; p < 4; ++p) accp[p] = fmaf(xs[p * 4 + rr][c], w, accp[p]);
  }
  #pragma unroll
  for (int p = 0; p < 4; ++p) {
    sgv[p] = sg[(base + p * 4 + rr) * 64 + cc];
    accp[p] += sgv[p];
  }
  __syncthreads();
  float qv[4];
  #pragma unroll
  for (int p = 0; p < 4; ++p) {
    const size_t idx = (base + p * 4 + rr) * 64 + cc;
    const float awg = row_ln(accp[p], g_[cc], b_[cc]);
    const float xv = qn[idx] + sgv[p] * sigmoidf(awg);
    qv[p] = row_ln(xv, lng[cc], lnb[cc]);
    qn_out[idx] = qv[p];
    xs[p * 4 + rr][cc] = qv[p];
  }
  __syncthreads();
  float d1[4], d2[4];
  #pragma unroll
  for (int p = 0; p < 4; ++p) { d1[p] = bb1[cc]; d2[p] = bb2[cc]; }
  #pragma unroll 4
  for (int c = 0; c < 64; ++c) {
    const float w1 = W1[c * 64 + cc];
    const float w2 = W2[c * 64 + cc];
    #pragma unroll
    for (int p = 0; p < 4; ++p) {
      const float xv = xs[p * 4 + rr][c];
      d1[p] = fmaf(xv, w1, d1[p]);
      d2[p] = fmaf(xv, w2, d2[p]);
    }
  }
  __syncthreads();
  float sv[4];
  #pragma unroll
  for (int p = 0; p < 4; ++p) {
    sv[p] = sigmoidf(d1[p]) * d2[p];
    sg_out[(base + p * 4 + rr) * 64 + cc] = sv[p];
    xs[p * 4 + rr][cc] = sv[p];
  }
  __syncthreads();
  float aq[4];
  #pragma unroll
  for (int p = 0; p < 4; ++p) aq[p] = 0.f;
  #pragma unroll 8
  for (int c = 0; c < 64; ++c) {
    const float w = Wq[c * 64 + cc];
    #pragma unroll
    for (int p = 0; p < 4; ++p) aq[p] = fmaf(xs[p * 4 + rr][c], w, aq[p]);
  }
  #pragma unroll
  for (int p = 0; p < 4; ++p) {
    const float v0 = aq[p] * 0.25f;
    const float vN = __shfl_xor(v0, 1);   // partner dim (cc^1)
    if (!(cc & 1))
      qp_out[(base + p * 4 + rr) * 32 + (cc >> 1)] = packh2(v0, vN);
  }
}

// ---------------------------------------------------------------------------
// Fused awg_out(layer 1) + head: out = sigmoid(x2 @ fcW + fcb).
// 16 rows/block, grid 750, 4 rows/thread, R12 unroll depth.
// ---------------------------------------------------------------------------
__global__ __launch_bounds__(256) void out_final_kernel(
    const float* __restrict__ ao, const float* __restrict__ sg,
    const float* __restrict__ qn, const float* __restrict__ Wo,
    const float* __restrict__ g_, const float* __restrict__ b_,
    const float* __restrict__ fw, const float* __restrict__ fb,
    float* __restrict__ out)
{
  __shared__ float xs[16][64];
  const int t = threadIdx.x, rr = t >> 6, cc = t & 63;
  const size_t base = (size_t)blockIdx.x * 16;
  for (int i = t; i < 1024; i += 256) xs[i >> 6][i & 63] = ao[base * 64 + i];
  __syncthreads();
  float accp[4];
  #pragma unroll
  for (int p = 0; p < 4; ++p) accp[p] = 0.f;
  #pragma unroll 8
  for (int c = 0; c < 64; ++c) {
    const float w = Wo[c * 64 + cc];
    #pragma unroll
    for (int p = 0; p < 4; ++p) accp[p] = fmaf(xs[p * 4 + rr][c], w, accp[p]);
  }
  #pragma unroll
  for (int p = 0; p < 4; ++p) {
    const size_t idx = (base + p * 4 + rr) * 64 + cc;
    const float sgv = sg[idx];
    const float a = accp[p] + sgv;
    const float awg = row_ln(a, g_[cc], b_[cc]);
    const float xv = qn[idx] + sgv * sigmoidf(awg);
    float v = xv * fw[cc];
    #pragma unroll
    for (int off = 32; off > 0; off >>= 1) v += __shfl_xor(v, off);
    if (cc == 0) out[base + p * 4 + rr] = sigmoidf(v + fb[0]);
  }
}

// ---------------------------------------------------------------------------
extern "C" void kernel_launch(void* const* d_in, const int* in_sizes, int n_in,
                              void* d_out, int out_size, void* d_ws, size_t ws_size,
                              hipStream_t stream) {
  (void)in_sizes; (void)n_in; (void)out_size; (void)ws_size;

  const float* q     = (const float*)d_in[0];
  const float* enc   = (const float*)d_in[1];
  const float* calWq = (const float*)d_in[2];
  const float* calWk = (const float*)d_in[3];
  const float* calWv = (const float*)d_in[4];
  const float* calWo = (const float*)d_in[5];
  const float* ln1g  = (const float*)d_in[6];
  const float* ln1b  = (const float*)d_in[7];
  const float* W1    = (const float*)d_in[8];
  const float* b1v   = (const float*)d_in[9];
  const float* W2    = (const float*)d_in[10];
  const float* b2v   = (const float*)d_in[11];
  const float* ln2g  = (const float*)d_in[12];
  const float* ln2b  = (const float*)d_in[13];
  const float* mlng  = (const float*)d_in[14];
  const float* mlnb  = (const float*)d_in[15];
  const float* mfc1W = (const float*)d_in[16];
  const float* mfc1b = (const float*)d_in[17];
  const float* mfc2W = (const float*)d_in[18];
  const float* mfc2b = (const float*)d_in[19];
  const float* mWq   = (const float*)d_in[20];
  const float* mWk   = (const float*)d_in[21];
  const float* mWv   = (const float*)d_in[22];
  const float* mWo   = (const float*)d_in[23];
  const float* malng = (const float*)d_in[24];
  const float* malnb = (const float*)d_in[25];
  const float* fcW   = (const float*)d_in[26];
  const float* fcb   = (const float*)d_in[27];
  float* out = (float*)d_out;

  float* ws  = (float*)d_ws;
  float* kv  = ws + WS_KV;
  float* qp  = ws + WS_QP;
  float* aob = ws + WS_AO;
  float* qnb = ws + WS_QN;
  float* sgb = ws + WS_SG;

  const size_t crossLds = (750 * 18 + 16 * 754 + 4 * 288) * 2;        // 53,432 B
  const size_t awgLds   = 4 * PITCH * 8 + 8192 + 4096 + 3072 + 1536;  // 40,928 B

  // 1) all K/V projections + cross q-projection in one dispatch
  //    (K slabs y==0/2/4 AND cal-V y==1 stored packed f16; mgan V f32)
  kvq_proj_kernel<<<dim3(750, 7), 256, 0, stream>>>(enc, q, calWq, calWk, calWv,
                                                    mWk, mWv, kv, qp);

  // 2) cross attention (MFMA flash-lite, pre-packed K+V) + fused FFN+MGAN-pre
  cross_attn_kernel<<<dim3(47, NH_, B_), 256, crossLds, stream>>>(
      qp, (const unsigned int*)kv, (const unsigned int*)(kv + 192000), aob);
  ffn_pre_kernel<<<750, 256, 0, stream>>>(aob, q, calWo, ln1g, ln1b,
                                          W1, b1v, W2, b2v, ln2g, ln2b,
                                          mlng, mlnb, mfc1W, mfc1b,
                                          mfc2W, mfc2b, mWq, qnb, sgb,
                                          (unsigned int*)qp);

  // 3) MGAN layer 0 attention + fused out/pre
  awg_attn_kernel<<<dim3(94, NH_, B_), 512, awgLds, stream>>>(
      (const unsigned int*)qp, (const unsigned int*)(kv + 2 * 192000),
      kv + 3 * 192000, aob);
  out_pre_kernel<<<750, 256, 0, stream>>>(aob, sgb, qnb, mWo, malng, malnb,
                                          mlng + 64, mlnb + 64,
                                          mfc1W + 4096, mfc1b + 64,
                                          mfc2W + 4096, mfc2b + 64,
                                          mWq + 4096, qnb, sgb,
                                          (unsigned int*)qp);

  // 4) MGAN layer 1 + head
  awg_attn_kernel<<<dim3(94, NH_, B_), 512, awgLds, stream>>>(
      (const unsigned int*)qp, (const unsigned int*)(kv + 4 * 192000),
      kv + 5 * 192000, aob);
  out_final_kernel<<<750, 256, 0, stream>>>(aob, sgb, qnb, mWo + 4096,
                                            malng + 64, malnb + 64, fcW, fcb, out);
}